// Round 13
// baseline (428.433 us; speedup 1.0000x reference)
//
#include <hip/hip_runtime.h>
#include <hip/hip_bf16.h>
#include <math.h>

#define DH 128
#define NRBF 16
#define EB 256     // edges per k_edge block (4 waves x 64 edges, 4 subtiles of 16)
#define NTAB 1025
#define SEGCAP 32  // max LDS-resident dst segments per block

typedef unsigned short ushort_t;
typedef __attribute__((ext_vector_type(8))) short short8;
typedef __attribute__((ext_vector_type(4))) float floatx4;

__device__ __forceinline__ float silu_f(float v) {
    return v / (1.f + __expf(-v));
}
__device__ __forceinline__ unsigned pk_bf16(float lo, float hi) {
    __hip_bfloat162 h = __float22bfloat162_rn(make_float2(lo, hi));
    union { __hip_bfloat162 h2; unsigned u; } cv;
    cv.h2 = h;
    return cv.u;
}
__device__ __forceinline__ ushort_t f2bf1(float f) {
    unsigned u = __float_as_uint(f);
    u += 0x7FFFu + ((u >> 16) & 1u);
    return (ushort_t)(u >> 16);
}
__device__ __forceinline__ float bflo(unsigned u) { return __uint_as_float(u << 16); }
__device__ __forceinline__ float bfhi(unsigned u) { return __uint_as_float(u & 0xffff0000u); }
__device__ __forceinline__ float bf2f(ushort_t u) { return __uint_as_float(((unsigned)u) << 16); }

__device__ __forceinline__ int detect64(const int* __restrict__ ei) {
    int z = 0;
#pragma unroll
    for (int i = 0; i < 8; ++i) z |= ei[2 * i + 1];
    return (z == 0) ? 1 : 0;
}
__device__ __forceinline__ int load_dst(const int* ei, int is64, int e, int E) {
    return is64 ? ei[2 * E + 2 * e] : ei[E + e];
}
__device__ __forceinline__ int load_src(const int* ei, int is64, int e, int E) {
    return is64 ? ei[2 * e] : ei[e];
}

#define PIN(u4) asm volatile("" :: "v"(u4.x), "v"(u4.y), "v"(u4.z), "v"(u4.w))

// ---------------------------------------------------------------------------
// Merged prep: histogram | Tbf rows (4/block) | W2f | W1mf | W1hf | W2hf
// ---------------------------------------------------------------------------
__global__ __launch_bounds__(256) void k_hist_prep(
    const int* __restrict__ ei, int* __restrict__ counts, int E,
    const float* __restrict__ Wm1, const float* __restrict__ Wm2,
    const float* __restrict__ Wh1, const float* __restrict__ Wh2,
    ushort_t* __restrict__ Tbf, ushort_t* __restrict__ W2f,
    ushort_t* __restrict__ W1mf, ushort_t* __restrict__ W1hf,
    ushort_t* __restrict__ W2hf, int nb_hist)
{
    const int b = blockIdx.x, tid = threadIdx.x;
    if (b < nb_hist) {
        const int e = b * 256 + tid;
        if (e < E) {
            const int is64 = detect64(ei);
            atomicAdd(&counts[load_dst(ei, is64, e, E)], 1);
        }
        return;
    }
    int b2 = b - nb_hist;
    if (b2 < 257) {
        const int i = b2 * 4 + (tid >> 6);
        if (i < NTAB) {
            const float WIDTH = 0.09428090415820634f;
            const float GAMMA = 56.25f;
            const float DELTA = 1.4142135623730951f / 1024.0f;
            const float r = (float)i * DELTA;
            const int c0 = (tid & 63) * 2;
            float a0 = 0.f, a1 = 0.f;
#pragma unroll
            for (int q = 0; q < NRBF; ++q) {
                const float dr = r - (float)q * WIDTH;
                const float w = __expf(-GAMMA * dr * dr);
                a0 = fmaf(w, Wm1[(256 + q) * DH + c0], a0);
                a1 = fmaf(w, Wm1[(256 + q) * DH + c0 + 1], a1);
            }
            *(unsigned*)(Tbf + (size_t)i * DH + c0) = pk_bf16(a0, a1);
        }
        return;
    }
    b2 -= 257;
    if (b2 < 8) {
        const int u = b2 * 256 + tid;
        const int col = u & 127, kclg = u >> 7;
        const int lg = kclg & 3, kc = kclg >> 2;
        unsigned o[4];
#pragma unroll
        for (int j = 0; j < 2; ++j) {
            o[j]     = pk_bf16(Wm2[(kc * 32 + 4 * lg + 2 * j) * DH + col],
                               Wm2[(kc * 32 + 4 * lg + 2 * j + 1) * DH + col]);
            o[2 + j] = pk_bf16(Wm2[(kc * 32 + 16 + 4 * lg + 2 * j) * DH + col],
                               Wm2[(kc * 32 + 16 + 4 * lg + 2 * j + 1) * DH + col]);
        }
        *(uint4*)(W2f + 8 * u) = make_uint4(o[0], o[1], o[2], o[3]);
        return;
    }
    b2 -= 8;
    if (b2 < 16) {
        const int u = b2 * 256 + tid;
        const int c = u & 255, kclg = u >> 8;
        const int lg = kclg & 3, kc = kclg >> 2;
        const int base = (c < 128) ? 0 : 128;
        const int cc = c & 127;
        unsigned o[4];
#pragma unroll
        for (int j = 0; j < 2; ++j) {
            o[j]     = pk_bf16(Wm1[(base + kc * 32 + 4 * lg + 2 * j) * DH + cc],
                               Wm1[(base + kc * 32 + 4 * lg + 2 * j + 1) * DH + cc]);
            o[2 + j] = pk_bf16(Wm1[(base + kc * 32 + 16 + 4 * lg + 2 * j) * DH + cc],
                               Wm1[(base + kc * 32 + 16 + 4 * lg + 2 * j + 1) * DH + cc]);
        }
        *(uint4*)(W1mf + 8 * u) = make_uint4(o[0], o[1], o[2], o[3]);
        return;
    }
    b2 -= 16;
    if (b2 < 16) {
        const int u = b2 * 256 + tid;
        const int col = u & 127, kclg = u >> 7;
        const int lg = kclg & 3, kc = kclg >> 2;
        unsigned o[4];
#pragma unroll
        for (int j = 0; j < 2; ++j) {
            o[j]     = pk_bf16(Wh1[(kc * 32 + 4 * lg + 2 * j) * DH + col],
                               Wh1[(kc * 32 + 4 * lg + 2 * j + 1) * DH + col]);
            o[2 + j] = pk_bf16(Wh1[(kc * 32 + 16 + 4 * lg + 2 * j) * DH + col],
                               Wh1[(kc * 32 + 16 + 4 * lg + 2 * j + 1) * DH + col]);
        }
        *(uint4*)(W1hf + 8 * u) = make_uint4(o[0], o[1], o[2], o[3]);
        return;
    }
    b2 -= 16;
    {
        const int u = b2 * 256 + tid;
        const int col = u & 127, kclg = u >> 7;
        const int lg = kclg & 3, kc = kclg >> 2;
        unsigned o[4];
#pragma unroll
        for (int j = 0; j < 2; ++j) {
            o[j]     = pk_bf16(Wh2[(kc * 32 + 4 * lg + 2 * j) * DH + col],
                               Wh2[(kc * 32 + 4 * lg + 2 * j + 1) * DH + col]);
            o[2 + j] = pk_bf16(Wh2[(kc * 32 + 16 + 4 * lg + 2 * j) * DH + col],
                               Wh2[(kc * 32 + 16 + 4 * lg + 2 * j + 1) * DH + col]);
        }
        *(uint4*)(W2hf + 8 * u) = make_uint4(o[0], o[1], o[2], o[3]);
    }
}

// ---------------------------------------------------------------------------
// Exclusive prefix sum of counts -> cursor.
// ---------------------------------------------------------------------------
__global__ __launch_bounds__(1024) void k_scan(const int* __restrict__ counts,
                                               int* __restrict__ cursor, int N) {
    __shared__ int wsum[16];
    __shared__ int sCarry;
    const int tid = threadIdx.x, lane = tid & 63, wid = tid >> 6;
    if (tid == 0) sCarry = 0;
    __syncthreads();
    for (int c0 = 0; c0 < N; c0 += 4096) {
        const int idx = c0 + tid * 4;
        int4 v = make_int4(0, 0, 0, 0);
        if (idx < N) v = *(const int4*)(counts + idx);
        const int t01 = v.x + v.y;
        const int t012 = t01 + v.z;
        const int tot = t012 + v.w;
        int incl = tot;
#pragma unroll
        for (int d = 1; d < 64; d <<= 1) {
            int t = __shfl_up(incl, d, 64);
            if (lane >= d) incl += t;
        }
        if (lane == 63) wsum[wid] = incl;
        __syncthreads();
        if (wid == 0) {
            int s = (lane < 16) ? wsum[lane] : 0;
#pragma unroll
            for (int d = 1; d < 16; d <<= 1) {
                int t = __shfl_up(s, d, 64);
                if (lane >= d) s += t;
            }
            if (lane < 16) wsum[lane] = s;
        }
        __syncthreads();
        const int ex = sCarry + (wid > 0 ? wsum[wid - 1] : 0) + incl - tot;
        if (idx + 3 < N) {
            *(int4*)(cursor + idx) = make_int4(ex, ex + v.x, ex + t01, ex + t012);
        } else if (idx < N) {
            cursor[idx] = ex;
            if (idx + 1 < N) cursor[idx + 1] = ex + v.x;
            if (idx + 2 < N) cursor[idx + 2] = ex + t01;
        }
        __syncthreads();
        if (tid == 0) sCarry += wsum[15];
        __syncthreads();
    }
}

// ---------------------------------------------------------------------------
// Merged: scatter packed 16B payloads | MFMA precompute A/B -> bf16
// ---------------------------------------------------------------------------
__global__ __launch_bounds__(256) void k_scatter_pre(
    const int* __restrict__ ei, const float* __restrict__ ew, const float* __restrict__ x,
    int* __restrict__ cursor, uint4* __restrict__ epk,
    int E, int pack,
    const float* __restrict__ h, const float* __restrict__ bm1,
    const ushort_t* __restrict__ W1mf,
    ushort_t* __restrict__ Abf, ushort_t* __restrict__ Bbf, int N, int nb_scat)
{
    const int tid = threadIdx.x;

    if ((int)blockIdx.x < nb_scat) {
        const int e = blockIdx.x * 256 + tid;
        if (e < E) {
            const int is64 = detect64(ei);
            const int s = load_src(ei, is64, e, E);
            const int d = load_dst(ei, is64, e, E);
            const int pos = atomicAdd(&cursor[d], 1);
            unsigned x0 = (unsigned)s;
            if (pack) {
                const float2 xs = *(const float2*)(x + 2 * s);
                const float2 xd = *(const float2*)(x + 2 * d);
                const float dxv = xs.x - xd.x, dyv = xs.y - xd.y;
                const float r = sqrtf(dxv * dxv + dyv * dyv + 1e-8f);
                int ti = (int)(r * 724.0773439350246f + 0.5f);
                ti = min(ti, NTAB - 1);
                x0 |= ((unsigned)ti << 16);
            }
            epk[pos] = make_uint4(x0, __float_as_uint(ew[e]), (unsigned)d, 0u);
        }
        return;
    }

    __shared__ __align__(16) ushort_t sIn[64 * DH];
    const int nblk = ((int)blockIdx.x - nb_scat) * 64;

    {
        const int row = tid >> 2, q = tid & 3;
        const int gn = nblk + row;
        const float4* ps = (const float4*)(h + (size_t)gn * DH + 32 * q);
        uint4* rowp = (uint4*)(sIn + row * DH);
        const int swz = row & 7;
#pragma unroll
        for (int i = 0; i < 4; ++i) {
            uint4 o = make_uint4(0, 0, 0, 0);
            if (gn < N) {
                const float4 g0 = ps[2 * i], g1 = ps[2 * i + 1];
                o.x = pk_bf16(g0.x, g0.y); o.y = pk_bf16(g0.z, g0.w);
                o.z = pk_bf16(g1.x, g1.y); o.w = pk_bf16(g1.z, g1.w);
            }
            rowp[(4 * q + i) ^ swz] = o;
        }
    }
    __syncthreads();

    const int lane = tid & 63, wv = tid >> 6;
    const int lr = lane & 15, lg = lane >> 4;
    const int m0l = wv * 16;

    union FragU { unsigned u[4]; short8 s8; };
    floatx4 acc[16];
#pragma unroll
    for (int ni = 0; ni < 16; ++ni) acc[ni] = (floatx4){0.f, 0.f, 0.f, 0.f};

#pragma unroll
    for (int kc = 0; kc < 4; ++kc) {
        const int b1 = 64 * kc + 8 * lg;
        const int b2 = b1 + 32;
        const int row = m0l + lr;
        const char* rbase = (const char*)(sIn + row * DH);
        const int swz = (row & 7) << 4;
        FragU af;
        const uint2 lo = *(const uint2*)(rbase + ((b1 & ~15) ^ swz) + (b1 & 15));
        const uint2 hi = *(const uint2*)(rbase + ((b2 & ~15) ^ swz) + (b2 & 15));
        af.u[0] = lo.x; af.u[1] = lo.y; af.u[2] = hi.x; af.u[3] = hi.y;
        const ushort_t* wbase = W1mf + ((size_t)(kc * 4 + lg) * 256 + lr) * 8;
        __builtin_amdgcn_s_setprio(1);
#pragma unroll
        for (int ni = 0; ni < 16; ++ni) {
            const short8 bf = *(const short8*)(wbase + ni * 128);
            acc[ni] = __builtin_amdgcn_mfma_f32_16x16x32_bf16(af.s8, bf, acc[ni], 0, 0, 0);
        }
        __builtin_amdgcn_s_setprio(0);
    }

    float bm1v[8];
#pragma unroll
    for (int ni = 0; ni < 8; ++ni) bm1v[ni] = bm1[ni * 16 + lr];
#pragma unroll
    for (int r = 0; r < 4; ++r) {
        const int gn = nblk + m0l + 4 * lg + r;
        if (gn < N) {
#pragma unroll
            for (int ni = 0; ni < 8; ++ni)
                Abf[(size_t)gn * DH + ni * 16 + lr] = f2bf1(acc[ni][r] + bm1v[ni]);
#pragma unroll
            for (int ni = 8; ni < 16; ++ni)
                Bbf[(size_t)gn * DH + (ni - 8) * 16 + lr] = f2bf1(acc[ni][r]);
        }
    }
}

// ---------------------------------------------------------------------------
// Edge kernel: 256 edges/block, 4 waves x 64 edges (4 subtiles of 16).
//  - ALL 4 subtiles' random A-rows prefetched up front, pinned live with
//    volatile asm (compiler cannot sink) -> gather latency paid once/wave.
//  - B/T (L2-hot) and W2f B-fragments loaded inline per subtile.
//  - per-wave sHid slices, barrier-free subtile loop, LDS segment agg.
// ---------------------------------------------------------------------------
__global__ __launch_bounds__(256, 2) void k_edge(
    const float* __restrict__ x, const int* __restrict__ ei, const float* __restrict__ ew,
    const uint4* __restrict__ epk,
    const ushort_t* __restrict__ W2f, const float* __restrict__ bm2,
    const ushort_t* __restrict__ Abf, const ushort_t* __restrict__ Bbf,
    const ushort_t* __restrict__ Tbf, float* __restrict__ agg,
    int sorted, int pack, int N, int E)
{
    __shared__ __align__(16) ushort_t sHid[4][16 * DH];   // 16 KB per-wave slices
    __shared__ __align__(16) float ldsAgg[SEGCAP][DH];    // 16 KB
    __shared__ int   sSrc[EB];
    __shared__ int   sDst[EB];
    __shared__ int   sLid[EB];
    __shared__ int   sTi[EB];
    __shared__ float sEw[EB];
    __shared__ int   sSegStart[SEGCAP];
    __shared__ int   sNseg;
    __shared__ int   sWtot[4];

    const int tid  = threadIdx.x;
    const int lane = tid & 63;
    const int wv   = tid >> 6;
    const int lr   = lane & 15;
    const int lg   = lane >> 4;
    const int e4   = lane >> 2;    // edge within 16-edge subtile
    const int q    = lane & 3;     // col quarter
    const int wbase = wv * 64;     // wave's 64-edge range within block

    // XCD-chunked bijective swizzle
    const int nwg = gridDim.x;
    const int xcd = blockIdx.x & 7;
    const int cidx = blockIdx.x >> 3;
    const int qch = nwg >> 3, rch = nwg & 7;
    const int bid = (xcd < rch) ? (xcd * (qch + 1) + cidx)
                                : (rch * (qch + 1) + (xcd - rch) * qch + cidx);
    const int e0 = bid * EB;

    // zero ldsAgg: 4096 floats = 1024 float4
    {
        const float4 z = make_float4(0.f, 0.f, 0.f, 0.f);
        float4* za = (float4*)&ldsAgg[0][0];
#pragma unroll
        for (int i = 0; i < 4; ++i) za[tid + 256 * i] = z;
    }

    // ---- staging: each thread stages one slot ----
    {
        const int slot = e0 + tid;
        int s = 0, d = 0, ti = 0;
        float w = 0.f;
        if (slot < E) {
            if (sorted) {
                const uint4 v = epk[slot];
                w = __uint_as_float(v.y);
                d = (int)v.z;
                if (pack) { s = (int)(v.x & 0xFFFFu); ti = (int)(v.x >> 16); }
                else {
                    s = (int)v.x;
                    const float2 xs = *(const float2*)(x + 2 * s);
                    const float2 xd = *(const float2*)(x + 2 * d);
                    const float dxv = xs.x - xd.x, dyv = xs.y - xd.y;
                    const float r = sqrtf(dxv * dxv + dyv * dyv + 1e-8f);
                    ti = min((int)(r * 724.0773439350246f + 0.5f), NTAB - 1);
                }
            } else {
                const int is64 = detect64(ei);
                s = load_src(ei, is64, slot, E);
                d = load_dst(ei, is64, slot, E);
                w = ew[slot];
                const float2 xs = *(const float2*)(x + 2 * s);
                const float2 xd = *(const float2*)(x + 2 * d);
                const float dxv = xs.x - xd.x, dyv = xs.y - xd.y;
                const float r = sqrtf(dxv * dxv + dyv * dyv + 1e-8f);
                ti = min((int)(r * 724.0773439350246f + 0.5f), NTAB - 1);
            }
        } else {
            d = sorted ? (int)epk[E - 1].z : load_dst(ei, detect64(ei), E - 1, E);
        }
        sSrc[tid] = s; sDst[tid] = d; sEw[tid] = w; sTi[tid] = ti;
    }
    __syncthreads();

    // ---- lid segment scan over 256 slots (4 waves + cross-wave prefix) ----
    {
        const int bflag = (tid > 0) && (sDst[tid] != sDst[tid - 1]);
        int incl = bflag;
#pragma unroll
        for (int dd = 1; dd < 64; dd <<= 1) {
            int t = __shfl_up(incl, dd, 64);
            if (lane >= dd) incl += t;
        }
        if (lane == 63) sWtot[wv] = incl;
        __syncthreads();
        int off = 0;
#pragma unroll
        for (int wq = 0; wq < 3; ++wq)
            if (wq < wv) off += sWtot[wq];
        incl += off;
        sLid[tid] = incl;
        if ((bflag || tid == 0) && incl < SEGCAP) sSegStart[incl] = tid;
        if (tid == EB - 1) sNseg = incl + 1;
    }
    __syncthreads();

    // ---- prefetch ALL 4 subtiles' A rows; pin live so loads can't sink ----
    uint4 pa0[4], pa1[4], pa2[4], pa3[4];
    {
        const uint4* p0 = (const uint4*)(Abf + (size_t)sSrc[wbase +  0 + e4] * DH + 32 * q);
        const uint4* p1 = (const uint4*)(Abf + (size_t)sSrc[wbase + 16 + e4] * DH + 32 * q);
        const uint4* p2 = (const uint4*)(Abf + (size_t)sSrc[wbase + 32 + e4] * DH + 32 * q);
        const uint4* p3 = (const uint4*)(Abf + (size_t)sSrc[wbase + 48 + e4] * DH + 32 * q);
#pragma unroll
        for (int i = 0; i < 4; ++i) pa0[i] = p0[i];
#pragma unroll
        for (int i = 0; i < 4; ++i) pa1[i] = p1[i];
#pragma unroll
        for (int i = 0; i < 4; ++i) pa2[i] = p2[i];
#pragma unroll
        for (int i = 0; i < 4; ++i) pa3[i] = p3[i];
#pragma unroll
        for (int i = 0; i < 4; ++i) PIN(pa0[i]);
#pragma unroll
        for (int i = 0; i < 4; ++i) PIN(pa1[i]);
#pragma unroll
        for (int i = 0; i < 4; ++i) PIN(pa2[i]);
#pragma unroll
        for (int i = 0; i < 4; ++i) PIN(pa3[i]);
    }

    float bc8[8];
#pragma unroll
    for (int ni = 0; ni < 8; ++ni) bc8[ni] = bm2[ni * 16 + lr];

    union FragU { unsigned u[4]; short8 s8; };
    ushort_t* slice = &sHid[wv][0];
    floatx4 acc[8];

#define SUBTILE(ST, PA)                                                         \
    {                                                                           \
        const int sb = wbase + (ST) * 16;                                       \
        const int le = sb + e4;                                                 \
        const int dS = sDst[le];                                                \
        const int tiS = sTi[le];                                                \
        const uint4* pB = (const uint4*)(Bbf + (size_t)dS * DH + 32 * q);       \
        const uint4* pT = (const uint4*)(Tbf + (size_t)tiS * DH + 32 * q);      \
        uint4 bv[4], tv[4];                                                     \
        _Pragma("unroll")                                                       \
        for (int i = 0; i < 4; ++i) { bv[i] = pB[i]; tv[i] = pT[i]; }           \
        {                                                                       \
            uint4* rowp = (uint4*)(slice + e4 * DH);                            \
            const int swzw = e4 & 7;                                            \
            _Pragma("unroll")                                                   \
            for (int i = 0; i < 4; ++i) {                                       \
                const uint4 a = PA[i]; const uint4 b = bv[i]; const uint4 t = tv[i]; \
                const float v0 = bflo(a.x) + bflo(b.x) + bflo(t.x);             \
                const float v1 = bfhi(a.x) + bfhi(b.x) + bfhi(t.x);             \
                const float v2 = bflo(a.y) + bflo(b.y) + bflo(t.y);             \
                const float v3 = bfhi(a.y) + bfhi(b.y) + bfhi(t.y);             \
                const float v4 = bflo(a.z) + bflo(b.z) + bflo(t.z);             \
                const float v5 = bfhi(a.z) + bfhi(b.z) + bfhi(t.z);             \
                const float v6 = bflo(a.w) + bflo(b.w) + bflo(t.w);             \
                const float v7 = bfhi(a.w) + bfhi(b.w) + bfhi(t.w);             \
                uint4 pk;                                                       \
                pk.x = pk_bf16(silu_f(v0), silu_f(v1));                         \
                pk.y = pk_bf16(silu_f(v2), silu_f(v3));                         \
                pk.z = pk_bf16(silu_f(v4), silu_f(v5));                         \
                pk.w = pk_bf16(silu_f(v6), silu_f(v7));                         \
                rowp[(4 * q + i) ^ swzw] = pk;                                  \
            }                                                                   \
        }                                                                       \
        _Pragma("unroll")                                                       \
        for (int ni = 0; ni < 8; ++ni) acc[ni] = (floatx4){0.f, 0.f, 0.f, 0.f}; \
        _Pragma("unroll")                                                       \
        for (int kc = 0; kc < 4; ++kc) {                                        \
            const int bo1 = 64 * kc + 8 * lg;                                   \
            const int bo2 = bo1 + 32;                                           \
            const char* rbase = (const char*)(slice + lr * DH);                 \
            const int swzf = (lr & 7) << 4;                                     \
            FragU af;                                                           \
            const uint2 lo = *(const uint2*)(rbase + ((bo1 & ~15) ^ swzf) + (bo1 & 15)); \
            const uint2 hi = *(const uint2*)(rbase + ((bo2 & ~15) ^ swzf) + (bo2 & 15)); \
            af.u[0] = lo.x; af.u[1] = lo.y; af.u[2] = hi.x; af.u[3] = hi.y;     \
            const ushort_t* wb2 = W2f + ((size_t)(kc * 4 + lg) * 128 + lr) * 8; \
            __builtin_amdgcn_s_setprio(1);                                      \
            _Pragma("unroll")                                                   \
            for (int ni = 0; ni < 8; ++ni) {                                    \
                const short8 bf = *(const short8*)(wb2 + ni * 128);             \
                acc[ni] = __builtin_amdgcn_mfma_f32_16x16x32_bf16(af.s8, bf, acc[ni], 0, 0, 0); \
            }                                                                   \
            __builtin_amdgcn_s_setprio(0);                                      \
        }                                                                       \
        {                                                                       \
            const int sbg = sb + 4 * lg;                                        \
            int lid4[4]; float ew4[4];                                          \
            _Pragma("unroll")                                                   \
            for (int r = 0; r < 4; ++r) { lid4[r] = sLid[sbg + r]; ew4[r] = sEw[sbg + r]; } \
            _Pragma("unroll")                                                   \
            for (int ni = 0; ni < 8; ++ni) {                                    \
                const int col = ni * 16 + lr;                                   \
                const float bc = bc8[ni];                                       \
                int cur = lid4[0], curSlot = sbg;                               \
                float avv = (acc[ni][0] + bc) * ew4[0];                         \
                _Pragma("unroll")                                               \
                for (int r = 1; r < 4; ++r) {                                   \
                    const int l2 = lid4[r];                                     \
                    const float v = (acc[ni][r] + bc) * ew4[r];                 \
                    if (l2 == cur) avv += v;                                    \
                    else {                                                      \
                        if (cur < SEGCAP) atomicAdd(&ldsAgg[cur][col], avv);    \
                        else atomicAdd(agg + (size_t)sDst[curSlot] * DH + col, avv); \
                        cur = l2; curSlot = sbg + r; avv = v;                   \
                    }                                                           \
                }                                                               \
                if (cur < SEGCAP) atomicAdd(&ldsAgg[cur][col], avv);            \
                else atomicAdd(agg + (size_t)sDst[curSlot] * DH + col, avv);    \
            }                                                                   \
        }                                                                       \
    }

    SUBTILE(0, pa0);
    SUBTILE(1, pa1);
    SUBTILE(2, pa2);
    SUBTILE(3, pa3);
#undef SUBTILE

    __syncthreads();

    // flush: interior segments plain store, boundary segments atomicAdd
    const int ns = sNseg;
    const int gmax = (ns < SEGCAP) ? ns : SEGCAP;
    for (int idx = tid; idx < (gmax << 7); idx += 256) {
        const int g = idx >> 7, col = idx & 127;
        const float v = ldsAgg[g][col];
        const int dst = sDst[sSegStart[g]];
        float* p = agg + (size_t)dst * DH + col;
        if (sorted && g > 0 && g < ns - 1) *p = v;
        else atomicAdd(p, v);
    }
}

// ---------------------------------------------------------------------------
// Node MLP via MFMA + residual + LayerNorm.
// ---------------------------------------------------------------------------
__global__ __launch_bounds__(256) void k_node(
    const float* __restrict__ h, const float* __restrict__ agg,
    const ushort_t* __restrict__ W1hf, const float* __restrict__ bh1,
    const ushort_t* __restrict__ W2hf, const float* __restrict__ bh2,
    const float* __restrict__ ln_g, const float* __restrict__ ln_b,
    float* __restrict__ out, int N)
{
    __shared__ __align__(16) ushort_t sIn[64 * 256];
    __shared__ __align__(16) ushort_t sHid[64 * DH];
    const int tid = threadIdx.x;
    const int nblk = blockIdx.x * 64;

    {
        const int row = tid >> 2, q = tid & 3;
        const int gn = nblk + row;
        const float4* ps = (q < 2) ? (const float4*)(h + (size_t)gn * DH + 64 * q)
                                   : (const float4*)(agg + (size_t)gn * DH + 64 * (q - 2));
        uint4* rowp = (uint4*)(sIn + row * 256);
        const int swz = row & 7;
#pragma unroll
        for (int i = 0; i < 8; ++i) {
            uint4 o = make_uint4(0, 0, 0, 0);
            if (gn < N) {
                const float4 g0 = ps[2 * i], g1 = ps[2 * i + 1];
                o.x = pk_bf16(g0.x, g0.y); o.y = pk_bf16(g0.z, g0.w);
                o.z = pk_bf16(g1.x, g1.y); o.w = pk_bf16(g1.z, g1.w);
            }
            rowp[(8 * q + i) ^ swz] = o;
        }
    }
    __syncthreads();

    const int lane = tid & 63, wv = tid >> 6;
    const int lr = lane & 15, lg = lane >> 4;
    const int m0l = wv * 16;

    union FragU { unsigned u[4]; short8 s8; };

    floatx4 acc[8];
#pragma unroll
    for (int ni = 0; ni < 8; ++ni) acc[ni] = (floatx4){0.f, 0.f, 0.f, 0.f};

#pragma unroll
    for (int kc = 0; kc < 8; ++kc) {
        const int b1 = 64 * kc + 8 * lg;
        const int b2 = b1 + 32;
        const int row = m0l + lr;
        const char* rbase = (const char*)(sIn + row * 256);
        const int swz = (row & 7) << 4;
        FragU af;
        const uint2 lo = *(const uint2*)(rbase + ((b1 & ~15) ^ swz) + (b1 & 15));
        const uint2 hi = *(const uint2*)(rbase + ((b2 & ~15) ^ swz) + (b2 & 15));
        af.u[0] = lo.x; af.u[1] = lo.y; af.u[2] = hi.x; af.u[3] = hi.y;
        const ushort_t* wbase = W1hf + ((size_t)(kc * 4 + lg) * 128 + lr) * 8;
        __builtin_amdgcn_s_setprio(1);
#pragma unroll
        for (int ni = 0; ni < 8; ++ni) {
            const short8 bf = *(const short8*)(wbase + ni * 128);
            acc[ni] = __builtin_amdgcn_mfma_f32_16x16x32_bf16(af.s8, bf, acc[ni], 0, 0, 0);
        }
        __builtin_amdgcn_s_setprio(0);
    }

    {
        float bh1v[8];
#pragma unroll
        for (int ni = 0; ni < 8; ++ni) bh1v[ni] = bh1[ni * 16 + lr];
#pragma unroll
        for (int r = 0; r < 4; ++r) {
            const int row = m0l + 4 * lg + r;
            const int swz = row & 7;
            ushort_t* rp = sHid + row * DH;
#pragma unroll
            for (int ni = 0; ni < 8; ++ni) {
                const int col = ni * 16 + lr;
                rp[(((col >> 3) ^ swz) << 3) + (col & 7)] =
                    f2bf1(silu_f(acc[ni][r] + bh1v[ni]));
            }
        }
    }

    floatx4 acc2[8];
#pragma unroll
    for (int ni = 0; ni < 8; ++ni) acc2[ni] = (floatx4){0.f, 0.f, 0.f, 0.f};

#pragma unroll
    for (int kc = 0; kc < 4; ++kc) {
        const int b1 = 64 * kc + 8 * lg;
        const int b2 = b1 + 32;
        const int row = m0l + lr;
        const char* rbase = (const char*)(sHid + row * DH);
        const int swz = (row & 7) << 4;
        FragU af;
        const uint2 lo = *(const uint2*)(rbase + ((b1 & ~15) ^ swz) + (b1 & 15));
        const uint2 hi = *(const uint2*)(rbase + ((b2 & ~15) ^ swz) + (b2 & 15));
        af.u[0] = lo.x; af.u[1] = lo.y; af.u[2] = hi.x; af.u[3] = hi.y;
        const ushort_t* wbase = W2hf + ((size_t)(kc * 4 + lg) * 128 + lr) * 8;
        __builtin_amdgcn_s_setprio(1);
#pragma unroll
        for (int ni = 0; ni < 8; ++ni) {
            const short8 bf = *(const short8*)(wbase + ni * 128);
            acc2[ni] = __builtin_amdgcn_mfma_f32_16x16x32_bf16(af.s8, bf, acc2[ni], 0, 0, 0);
        }
        __builtin_amdgcn_s_setprio(0);
    }

    float gv[8], bv[8], b2v[8];
#pragma unroll
    for (int ni = 0; ni < 8; ++ni) {
        const int col = ni * 16 + lr;
        gv[ni] = ln_g[col]; bv[ni] = ln_b[col]; b2v[ni] = bh2[col];
    }
#pragma unroll
    for (int r = 0; r < 4; ++r) {
        const int row = m0l + 4 * lg + r;
        const int gn = nblk + row;
        const int swz = row & 7;
        float z[8];
        float s1 = 0.f, s2 = 0.f;
#pragma unroll
        for (int ni = 0; ni < 8; ++ni) {
            const int col = ni * 16 + lr;
            const float hv = bf2f(sIn[row * 256 + (((col >> 3) ^ swz) << 3) + (col & 7)]);
            z[ni] = acc2[ni][r] + b2v[ni] + hv;
            s1 += z[ni]; s2 += z[ni] * z[ni];
        }
#pragma unroll
        for (int m = 1; m < 16; m <<= 1) {
            s1 += __shfl_xor(s1, m, 64);
            s2 += __shfl_xor(s2, m, 64);
        }
        const float mean = s1 * (1.f / 128.f);
        const float var = s2 * (1.f / 128.f) - mean * mean;
        const float rstd = rsqrtf(var + 1e-5f);
        if (gn < N) {
#pragma unroll
            for (int ni = 0; ni < 8; ++ni) {
                const int col = ni * 16 + lr;
                out[(size_t)gn * DH + col] = (z[ni] - mean) * rstd * gv[ni] + bv[ni];
            }
        }
    }
}

extern "C" void kernel_launch(void* const* d_in, const int* in_sizes, int n_in,
                              void* d_out, int out_size, void* d_ws, size_t ws_size,
                              hipStream_t stream)
{
    (void)n_in; (void)out_size;
    const float* h   = (const float*)d_in[0];
    const float* x   = (const float*)d_in[1];
    const int*   ei  = (const int*)d_in[2];
    const float* ew  = (const float*)d_in[3];
    const float* Wm1 = (const float*)d_in[4];
    const float* bm1 = (const float*)d_in[5];
    const float* Wm2 = (const float*)d_in[6];
    const float* bm2 = (const float*)d_in[7];
    const float* Wh1 = (const float*)d_in[8];
    const float* bh1 = (const float*)d_in[9];
    const float* Wh2 = (const float*)d_in[10];
    const float* bh2 = (const float*)d_in[11];
    const float* lng = (const float*)d_in[12];
    const float* lnb = (const float*)d_in[13];
    float* out = (float*)d_out;

    const int N = in_sizes[0] / DH;
    const int E = in_sizes[3];

    // ws: agg | counts | cursor | Abf | Bbf | W2f | Tbf | W1mf | W1hf | W2hf | epk
    float*    agg  = (float*)d_ws;
    int*   counts  = (int*)(agg + (size_t)N * DH);
    int*   cursor  = counts + N;
    ushort_t* Abf  = (ushort_t*)((((uintptr_t)(cursor + N)) + 15) & ~(uintptr_t)15);
    ushort_t* Bbf  = Abf + (size_t)N * DH;
    ushort_t* W2f  = Bbf + (size_t)N * DH;
    ushort_t* Tbf  = W2f + 16384;
    ushort_t* W1mf = Tbf + (size_t)NTAB * DH;
    ushort_t* W1hf = W1mf + 32768;
    ushort_t* W2hf = W1hf + 32768;
    uint4* epk     = (uint4*)((((uintptr_t)(W2hf + 16384)) + 15) & ~(uintptr_t)15);

    const size_t need = ((char*)(epk + E)) - ((char*)d_ws);
    const int use_sort = (ws_size >= need) ? 1 : 0;
    const int pack = use_sort && (N <= 65535);

    const int nb_hist = use_sort ? (E + 255) / 256 : 0;
    const int nb_prep = 257 + 8 + 16 + 16 + 8;
    const int nb_scat = nb_hist;
    const int nb_pre  = (N + 63) / 64;

    // one memset covers agg and (contiguous) counts
    hipMemsetAsync(agg, 0, (size_t)N * DH * sizeof(float) + (use_sort ? (size_t)N * 4 : 0), stream);
    k_hist_prep<<<nb_hist + nb_prep, 256, 0, stream>>>(ei, counts, E, Wm1, Wm2, Wh1, Wh2,
                                                       Tbf, W2f, W1mf, W1hf, W2hf, nb_hist);
    if (use_sort)
        k_scan<<<1, 1024, 0, stream>>>(counts, cursor, N);
    k_scatter_pre<<<nb_scat + nb_pre, 256, 0, stream>>>(ei, ew, x, cursor, epk, E, pack,
                                                        h, bm1, W1mf, Abf, Bbf, N, nb_scat);
    k_edge<<<(E + EB - 1) / EB, 256, 0, stream>>>(x, ei, ew, epk,
                                                  W2f, bm2, Abf, Bbf, Tbf, agg,
                                                  use_sort, pack, N, E);
    k_node<<<(N + 63) / 64, 256, 0, stream>>>(h, agg, W1hf, bh1, W2hf, bh2, lng, lnb, out, N);
}

// Round 14
// 403.694 us; speedup vs baseline: 1.0613x; 1.0613x over previous
//
#include <hip/hip_runtime.h>
#include <hip/hip_bf16.h>
#include <math.h>

#define DH 128
#define NRBF 16
#define EB 256     // edges per k_edge block (4 waves x 64 edges, 4 subtiles of 16)
#define NTAB 1025
#define SEGCAP 32  // max LDS-resident dst segments per block

typedef unsigned short ushort_t;
typedef __attribute__((ext_vector_type(8))) short short8;
typedef __attribute__((ext_vector_type(4))) float floatx4;

__device__ __forceinline__ float silu_f(float v) {
    return v / (1.f + __expf(-v));
}
__device__ __forceinline__ unsigned pk_bf16(float lo, float hi) {
    __hip_bfloat162 h = __float22bfloat162_rn(make_float2(lo, hi));
    union { __hip_bfloat162 h2; unsigned u; } cv;
    cv.h2 = h;
    return cv.u;
}
__device__ __forceinline__ ushort_t f2bf1(float f) {
    unsigned u = __float_as_uint(f);
    u += 0x7FFFu + ((u >> 16) & 1u);
    return (ushort_t)(u >> 16);
}
__device__ __forceinline__ float bflo(unsigned u) { return __uint_as_float(u << 16); }
__device__ __forceinline__ float bfhi(unsigned u) { return __uint_as_float(u & 0xffff0000u); }
__device__ __forceinline__ float bf2f(ushort_t u) { return __uint_as_float(((unsigned)u) << 16); }

__device__ __forceinline__ int detect64(const int* __restrict__ ei) {
    int z = 0;
#pragma unroll
    for (int i = 0; i < 8; ++i) z |= ei[2 * i + 1];
    return (z == 0) ? 1 : 0;
}
__device__ __forceinline__ int load_dst(const int* ei, int is64, int e, int E) {
    return is64 ? ei[2 * E + 2 * e] : ei[E + e];
}
__device__ __forceinline__ int load_src(const int* ei, int is64, int e, int E) {
    return is64 ? ei[2 * e] : ei[e];
}

// ---------------------------------------------------------------------------
// Merged prep: histogram | Tbf rows (4/block) | W2f | W1mf | W1hf | W2hf
// ---------------------------------------------------------------------------
__global__ __launch_bounds__(256) void k_hist_prep(
    const int* __restrict__ ei, int* __restrict__ counts, int E,
    const float* __restrict__ Wm1, const float* __restrict__ Wm2,
    const float* __restrict__ Wh1, const float* __restrict__ Wh2,
    ushort_t* __restrict__ Tbf, ushort_t* __restrict__ W2f,
    ushort_t* __restrict__ W1mf, ushort_t* __restrict__ W1hf,
    ushort_t* __restrict__ W2hf, int nb_hist)
{
    const int b = blockIdx.x, tid = threadIdx.x;
    if (b < nb_hist) {
        const int e = b * 256 + tid;
        if (e < E) {
            const int is64 = detect64(ei);
            atomicAdd(&counts[load_dst(ei, is64, e, E)], 1);
        }
        return;
    }
    int b2 = b - nb_hist;
    if (b2 < 257) {
        const int i = b2 * 4 + (tid >> 6);
        if (i < NTAB) {
            const float WIDTH = 0.09428090415820634f;
            const float GAMMA = 56.25f;
            const float DELTA = 1.4142135623730951f / 1024.0f;
            const float r = (float)i * DELTA;
            const int c0 = (tid & 63) * 2;
            float a0 = 0.f, a1 = 0.f;
#pragma unroll
            for (int q = 0; q < NRBF; ++q) {
                const float dr = r - (float)q * WIDTH;
                const float w = __expf(-GAMMA * dr * dr);
                a0 = fmaf(w, Wm1[(256 + q) * DH + c0], a0);
                a1 = fmaf(w, Wm1[(256 + q) * DH + c0 + 1], a1);
            }
            *(unsigned*)(Tbf + (size_t)i * DH + c0) = pk_bf16(a0, a1);
        }
        return;
    }
    b2 -= 257;
    if (b2 < 8) {
        const int u = b2 * 256 + tid;
        const int col = u & 127, kclg = u >> 7;
        const int lg = kclg & 3, kc = kclg >> 2;
        unsigned o[4];
#pragma unroll
        for (int j = 0; j < 2; ++j) {
            o[j]     = pk_bf16(Wm2[(kc * 32 + 4 * lg + 2 * j) * DH + col],
                               Wm2[(kc * 32 + 4 * lg + 2 * j + 1) * DH + col]);
            o[2 + j] = pk_bf16(Wm2[(kc * 32 + 16 + 4 * lg + 2 * j) * DH + col],
                               Wm2[(kc * 32 + 16 + 4 * lg + 2 * j + 1) * DH + col]);
        }
        *(uint4*)(W2f + 8 * u) = make_uint4(o[0], o[1], o[2], o[3]);
        return;
    }
    b2 -= 8;
    if (b2 < 16) {
        const int u = b2 * 256 + tid;
        const int c = u & 255, kclg = u >> 8;
        const int lg = kclg & 3, kc = kclg >> 2;
        const int base = (c < 128) ? 0 : 128;
        const int cc = c & 127;
        unsigned o[4];
#pragma unroll
        for (int j = 0; j < 2; ++j) {
            o[j]     = pk_bf16(Wm1[(base + kc * 32 + 4 * lg + 2 * j) * DH + cc],
                               Wm1[(base + kc * 32 + 4 * lg + 2 * j + 1) * DH + cc]);
            o[2 + j] = pk_bf16(Wm1[(base + kc * 32 + 16 + 4 * lg + 2 * j) * DH + cc],
                               Wm1[(base + kc * 32 + 16 + 4 * lg + 2 * j + 1) * DH + cc]);
        }
        *(uint4*)(W1mf + 8 * u) = make_uint4(o[0], o[1], o[2], o[3]);
        return;
    }
    b2 -= 16;
    if (b2 < 16) {
        const int u = b2 * 256 + tid;
        const int col = u & 127, kclg = u >> 7;
        const int lg = kclg & 3, kc = kclg >> 2;
        unsigned o[4];
#pragma unroll
        for (int j = 0; j < 2; ++j) {
            o[j]     = pk_bf16(Wh1[(kc * 32 + 4 * lg + 2 * j) * DH + col],
                               Wh1[(kc * 32 + 4 * lg + 2 * j + 1) * DH + col]);
            o[2 + j] = pk_bf16(Wh1[(kc * 32 + 16 + 4 * lg + 2 * j) * DH + col],
                               Wh1[(kc * 32 + 16 + 4 * lg + 2 * j + 1) * DH + col]);
        }
        *(uint4*)(W1hf + 8 * u) = make_uint4(o[0], o[1], o[2], o[3]);
        return;
    }
    b2 -= 16;
    {
        const int u = b2 * 256 + tid;
        const int col = u & 127, kclg = u >> 7;
        const int lg = kclg & 3, kc = kclg >> 2;
        unsigned o[4];
#pragma unroll
        for (int j = 0; j < 2; ++j) {
            o[j]     = pk_bf16(Wh2[(kc * 32 + 4 * lg + 2 * j) * DH + col],
                               Wh2[(kc * 32 + 4 * lg + 2 * j + 1) * DH + col]);
            o[2 + j] = pk_bf16(Wh2[(kc * 32 + 16 + 4 * lg + 2 * j) * DH + col],
                               Wh2[(kc * 32 + 16 + 4 * lg + 2 * j + 1) * DH + col]);
        }
        *(uint4*)(W2hf + 8 * u) = make_uint4(o[0], o[1], o[2], o[3]);
    }
}

// ---------------------------------------------------------------------------
// Exclusive prefix sum of counts -> cursor.
// ---------------------------------------------------------------------------
__global__ __launch_bounds__(1024) void k_scan(const int* __restrict__ counts,
                                               int* __restrict__ cursor, int N) {
    __shared__ int wsum[16];
    __shared__ int sCarry;
    const int tid = threadIdx.x, lane = tid & 63, wid = tid >> 6;
    if (tid == 0) sCarry = 0;
    __syncthreads();
    for (int c0 = 0; c0 < N; c0 += 4096) {
        const int idx = c0 + tid * 4;
        int4 v = make_int4(0, 0, 0, 0);
        if (idx < N) v = *(const int4*)(counts + idx);
        const int t01 = v.x + v.y;
        const int t012 = t01 + v.z;
        const int tot = t012 + v.w;
        int incl = tot;
#pragma unroll
        for (int d = 1; d < 64; d <<= 1) {
            int t = __shfl_up(incl, d, 64);
            if (lane >= d) incl += t;
        }
        if (lane == 63) wsum[wid] = incl;
        __syncthreads();
        if (wid == 0) {
            int s = (lane < 16) ? wsum[lane] : 0;
#pragma unroll
            for (int d = 1; d < 16; d <<= 1) {
                int t = __shfl_up(s, d, 64);
                if (lane >= d) s += t;
            }
            if (lane < 16) wsum[lane] = s;
        }
        __syncthreads();
        const int ex = sCarry + (wid > 0 ? wsum[wid - 1] : 0) + incl - tot;
        if (idx + 3 < N) {
            *(int4*)(cursor + idx) = make_int4(ex, ex + v.x, ex + t01, ex + t012);
        } else if (idx < N) {
            cursor[idx] = ex;
            if (idx + 1 < N) cursor[idx + 1] = ex + v.x;
            if (idx + 2 < N) cursor[idx + 2] = ex + t01;
        }
        __syncthreads();
        if (tid == 0) sCarry += wsum[15];
        __syncthreads();
    }
}

// ---------------------------------------------------------------------------
// Merged: scatter packed 16B payloads | MFMA precompute A/B -> bf16
// ---------------------------------------------------------------------------
__global__ __launch_bounds__(256) void k_scatter_pre(
    const int* __restrict__ ei, const float* __restrict__ ew, const float* __restrict__ x,
    int* __restrict__ cursor, uint4* __restrict__ epk,
    int E, int pack,
    const float* __restrict__ h, const float* __restrict__ bm1,
    const ushort_t* __restrict__ W1mf,
    ushort_t* __restrict__ Abf, ushort_t* __restrict__ Bbf, int N, int nb_scat)
{
    const int tid = threadIdx.x;

    if ((int)blockIdx.x < nb_scat) {
        const int e = blockIdx.x * 256 + tid;
        if (e < E) {
            const int is64 = detect64(ei);
            const int s = load_src(ei, is64, e, E);
            const int d = load_dst(ei, is64, e, E);
            const int pos = atomicAdd(&cursor[d], 1);
            unsigned x0 = (unsigned)s;
            if (pack) {
                const float2 xs = *(const float2*)(x + 2 * s);
                const float2 xd = *(const float2*)(x + 2 * d);
                const float dxv = xs.x - xd.x, dyv = xs.y - xd.y;
                const float r = sqrtf(dxv * dxv + dyv * dyv + 1e-8f);
                int ti = (int)(r * 724.0773439350246f + 0.5f);
                ti = min(ti, NTAB - 1);
                x0 |= ((unsigned)ti << 16);
            }
            epk[pos] = make_uint4(x0, __float_as_uint(ew[e]), (unsigned)d, 0u);
        }
        return;
    }

    __shared__ __align__(16) ushort_t sIn[64 * DH];
    const int nblk = ((int)blockIdx.x - nb_scat) * 64;

    {
        const int row = tid >> 2, q = tid & 3;
        const int gn = nblk + row;
        const float4* ps = (const float4*)(h + (size_t)gn * DH + 32 * q);
        uint4* rowp = (uint4*)(sIn + row * DH);
        const int swz = row & 7;
#pragma unroll
        for (int i = 0; i < 4; ++i) {
            uint4 o = make_uint4(0, 0, 0, 0);
            if (gn < N) {
                const float4 g0 = ps[2 * i], g1 = ps[2 * i + 1];
                o.x = pk_bf16(g0.x, g0.y); o.y = pk_bf16(g0.z, g0.w);
                o.z = pk_bf16(g1.x, g1.y); o.w = pk_bf16(g1.z, g1.w);
            }
            rowp[(4 * q + i) ^ swz] = o;
        }
    }
    __syncthreads();

    const int lane = tid & 63, wv = tid >> 6;
    const int lr = lane & 15, lg = lane >> 4;
    const int m0l = wv * 16;

    union FragU { unsigned u[4]; short8 s8; };
    floatx4 acc[16];
#pragma unroll
    for (int ni = 0; ni < 16; ++ni) acc[ni] = (floatx4){0.f, 0.f, 0.f, 0.f};

#pragma unroll
    for (int kc = 0; kc < 4; ++kc) {
        const int b1 = 64 * kc + 8 * lg;
        const int b2 = b1 + 32;
        const int row = m0l + lr;
        const char* rbase = (const char*)(sIn + row * DH);
        const int swz = (row & 7) << 4;
        FragU af;
        const uint2 lo = *(const uint2*)(rbase + ((b1 & ~15) ^ swz) + (b1 & 15));
        const uint2 hi = *(const uint2*)(rbase + ((b2 & ~15) ^ swz) + (b2 & 15));
        af.u[0] = lo.x; af.u[1] = lo.y; af.u[2] = hi.x; af.u[3] = hi.y;
        const ushort_t* wbase = W1mf + ((size_t)(kc * 4 + lg) * 256 + lr) * 8;
        __builtin_amdgcn_s_setprio(1);
#pragma unroll
        for (int ni = 0; ni < 16; ++ni) {
            const short8 bf = *(const short8*)(wbase + ni * 128);
            acc[ni] = __builtin_amdgcn_mfma_f32_16x16x32_bf16(af.s8, bf, acc[ni], 0, 0, 0);
        }
        __builtin_amdgcn_s_setprio(0);
    }

    float bm1v[8];
#pragma unroll
    for (int ni = 0; ni < 8; ++ni) bm1v[ni] = bm1[ni * 16 + lr];
#pragma unroll
    for (int r = 0; r < 4; ++r) {
        const int gn = nblk + m0l + 4 * lg + r;
        if (gn < N) {
#pragma unroll
            for (int ni = 0; ni < 8; ++ni)
                Abf[(size_t)gn * DH + ni * 16 + lr] = f2bf1(acc[ni][r] + bm1v[ni]);
#pragma unroll
            for (int ni = 8; ni < 16; ++ni)
                Bbf[(size_t)gn * DH + (ni - 8) * 16 + lr] = f2bf1(acc[ni][r]);
        }
    }
}

// ---------------------------------------------------------------------------
// Edge kernel: 256 edges/block, 4 waves x 64 edges (4 subtiles of 16).
//  - R12 structure (inline per-subtile A/B/T gathers, NO pin-prefetch).
//  - launch_bounds(256,4): VGPR cap 128 (body needs ~120) -> 4 blocks/CU
//    residency (LDS 38.4KB x 4 = 153.6 <= 160 KB) to hide gather latency.
// ---------------------------------------------------------------------------
__global__ __launch_bounds__(256, 4) void k_edge(
    const float* __restrict__ x, const int* __restrict__ ei, const float* __restrict__ ew,
    const uint4* __restrict__ epk,
    const ushort_t* __restrict__ W2f, const float* __restrict__ bm2,
    const ushort_t* __restrict__ Abf, const ushort_t* __restrict__ Bbf,
    const ushort_t* __restrict__ Tbf, float* __restrict__ agg,
    int sorted, int pack, int N, int E)
{
    __shared__ __align__(16) ushort_t sHid[4][16 * DH];   // 16 KB per-wave slices
    __shared__ __align__(16) float ldsAgg[SEGCAP][DH];    // 16 KB
    __shared__ int   sSrc[EB];
    __shared__ int   sDst[EB];
    __shared__ int   sLid[EB];
    __shared__ int   sTi[EB];
    __shared__ float sEw[EB];
    __shared__ int   sSegStart[SEGCAP];
    __shared__ int   sNseg;
    __shared__ int   sWtot[4];

    const int tid  = threadIdx.x;
    const int lane = tid & 63;
    const int wv   = tid >> 6;
    const int lr   = lane & 15;
    const int lg   = lane >> 4;
    const int e4   = lane >> 2;    // edge within 16-edge subtile
    const int q    = lane & 3;     // col quarter
    const int wbase = wv * 64;     // wave's 64-edge range within block

    // XCD-chunked bijective swizzle
    const int nwg = gridDim.x;
    const int xcd = blockIdx.x & 7;
    const int cidx = blockIdx.x >> 3;
    const int qch = nwg >> 3, rch = nwg & 7;
    const int bid = (xcd < rch) ? (xcd * (qch + 1) + cidx)
                                : (rch * (qch + 1) + (xcd - rch) * qch + cidx);
    const int e0 = bid * EB;

    // zero ldsAgg: 4096 floats = 1024 float4
    {
        const float4 z = make_float4(0.f, 0.f, 0.f, 0.f);
        float4* za = (float4*)&ldsAgg[0][0];
#pragma unroll
        for (int i = 0; i < 4; ++i) za[tid + 256 * i] = z;
    }

    // ---- staging: each thread stages one slot ----
    {
        const int slot = e0 + tid;
        int s = 0, d = 0, ti = 0;
        float w = 0.f;
        if (slot < E) {
            if (sorted) {
                const uint4 v = epk[slot];
                w = __uint_as_float(v.y);
                d = (int)v.z;
                if (pack) { s = (int)(v.x & 0xFFFFu); ti = (int)(v.x >> 16); }
                else {
                    s = (int)v.x;
                    const float2 xs = *(const float2*)(x + 2 * s);
                    const float2 xd = *(const float2*)(x + 2 * d);
                    const float dxv = xs.x - xd.x, dyv = xs.y - xd.y;
                    const float r = sqrtf(dxv * dxv + dyv * dyv + 1e-8f);
                    ti = min((int)(r * 724.0773439350246f + 0.5f), NTAB - 1);
                }
            } else {
                const int is64 = detect64(ei);
                s = load_src(ei, is64, slot, E);
                d = load_dst(ei, is64, slot, E);
                w = ew[slot];
                const float2 xs = *(const float2*)(x + 2 * s);
                const float2 xd = *(const float2*)(x + 2 * d);
                const float dxv = xs.x - xd.x, dyv = xs.y - xd.y;
                const float r = sqrtf(dxv * dxv + dyv * dyv + 1e-8f);
                ti = min((int)(r * 724.0773439350246f + 0.5f), NTAB - 1);
            }
        } else {
            d = sorted ? (int)epk[E - 1].z : load_dst(ei, detect64(ei), E - 1, E);
        }
        sSrc[tid] = s; sDst[tid] = d; sEw[tid] = w; sTi[tid] = ti;
    }
    __syncthreads();

    // ---- lid segment scan over 256 slots (4 waves + cross-wave prefix) ----
    {
        const int bflag = (tid > 0) && (sDst[tid] != sDst[tid - 1]);
        int incl = bflag;
#pragma unroll
        for (int dd = 1; dd < 64; dd <<= 1) {
            int t = __shfl_up(incl, dd, 64);
            if (lane >= dd) incl += t;
        }
        if (lane == 63) sWtot[wv] = incl;
        __syncthreads();
        int off = 0;
#pragma unroll
        for (int wq = 0; wq < 3; ++wq)
            if (wq < wv) off += sWtot[wq];
        incl += off;
        sLid[tid] = incl;
        if ((bflag || tid == 0) && incl < SEGCAP) sSegStart[incl] = tid;
        if (tid == EB - 1) sNseg = incl + 1;
    }
    __syncthreads();

    float bc8[8];
#pragma unroll
    for (int ni = 0; ni < 8; ++ni) bc8[ni] = bm2[ni * 16 + lr];

    union FragU { unsigned u[4]; short8 s8; };
    ushort_t* slice = &sHid[wv][0];
    floatx4 acc[8];

    // ---- barrier-free 4-subtile loop ----
#pragma unroll
    for (int st = 0; st < 4; ++st) {
        const int sb = wbase + st * 16;

        // gather A/B/T for edge sb+e4, cols 32q..32q+31
        const int le = sb + e4;
        const int s  = sSrc[le];
        const int d  = sDst[le];
        const int ti = sTi[le];
        const uint4* pA = (const uint4*)(Abf + (size_t)s * DH + 32 * q);
        const uint4* pB = (const uint4*)(Bbf + (size_t)d * DH + 32 * q);
        const uint4* pT = (const uint4*)(Tbf + (size_t)ti * DH + 32 * q);
        uint4 av[4], bv[4], tv[4];
#pragma unroll
        for (int i = 0; i < 4; ++i) { av[i] = pA[i]; bv[i] = pB[i]; tv[i] = pT[i]; }

        // BUILD hidden -> per-wave slice (swizzled bf16)
        {
            uint4* rowp = (uint4*)(slice + e4 * DH);
            const int swzw = e4 & 7;
#pragma unroll
            for (int i = 0; i < 4; ++i) {
                const uint4 a = av[i]; const uint4 b = bv[i]; const uint4 t = tv[i];
                const float v0 = bflo(a.x) + bflo(b.x) + bflo(t.x);
                const float v1 = bfhi(a.x) + bfhi(b.x) + bfhi(t.x);
                const float v2 = bflo(a.y) + bflo(b.y) + bflo(t.y);
                const float v3 = bfhi(a.y) + bfhi(b.y) + bfhi(t.y);
                const float v4 = bflo(a.z) + bflo(b.z) + bflo(t.z);
                const float v5 = bfhi(a.z) + bfhi(b.z) + bfhi(t.z);
                const float v6 = bflo(a.w) + bflo(b.w) + bflo(t.w);
                const float v7 = bfhi(a.w) + bfhi(b.w) + bfhi(t.w);
                uint4 pk;
                pk.x = pk_bf16(silu_f(v0), silu_f(v1));
                pk.y = pk_bf16(silu_f(v2), silu_f(v3));
                pk.z = pk_bf16(silu_f(v4), silu_f(v5));
                pk.w = pk_bf16(silu_f(v6), silu_f(v7));
                rowp[(4 * q + i) ^ swzw] = pk;
            }
        }
        // no barrier: wave reads only rows it wrote (in-wave LDS ordering)

        // MFMA: A from LDS (2 small reads/kc), B from global W2f (L2-hot)
#pragma unroll
        for (int ni = 0; ni < 8; ++ni) acc[ni] = (floatx4){0.f, 0.f, 0.f, 0.f};
#pragma unroll
        for (int kc = 0; kc < 4; ++kc) {
            const int bo1 = 64 * kc + 8 * lg;
            const int bo2 = bo1 + 32;
            const char* rbase = (const char*)(slice + lr * DH);
            const int swzf = (lr & 7) << 4;
            FragU af;
            const uint2 lo = *(const uint2*)(rbase + ((bo1 & ~15) ^ swzf) + (bo1 & 15));
            const uint2 hi = *(const uint2*)(rbase + ((bo2 & ~15) ^ swzf) + (bo2 & 15));
            af.u[0] = lo.x; af.u[1] = lo.y; af.u[2] = hi.x; af.u[3] = hi.y;
            const ushort_t* wb2 = W2f + ((size_t)(kc * 4 + lg) * 128 + lr) * 8;
            __builtin_amdgcn_s_setprio(1);
#pragma unroll
            for (int ni = 0; ni < 8; ++ni) {
                const short8 bf = *(const short8*)(wb2 + ni * 128);
                acc[ni] = __builtin_amdgcn_mfma_f32_16x16x32_bf16(af.s8, bf, acc[ni], 0, 0, 0);
            }
            __builtin_amdgcn_s_setprio(0);
        }

        // PHASE3: run-merge by lid -> LDS segment accumulation
        {
            const int sbg = sb + 4 * lg;
            int lid4[4]; float ew4[4];
#pragma unroll
            for (int r = 0; r < 4; ++r) { lid4[r] = sLid[sbg + r]; ew4[r] = sEw[sbg + r]; }
#pragma unroll
            for (int ni = 0; ni < 8; ++ni) {
                const int col = ni * 16 + lr;
                const float bc = bc8[ni];
                int cur = lid4[0], curSlot = sbg;
                float avv = (acc[ni][0] + bc) * ew4[0];
#pragma unroll
                for (int r = 1; r < 4; ++r) {
                    const int l2 = lid4[r];
                    const float v = (acc[ni][r] + bc) * ew4[r];
                    if (l2 == cur) avv += v;
                    else {
                        if (cur < SEGCAP) atomicAdd(&ldsAgg[cur][col], avv);
                        else atomicAdd(agg + (size_t)sDst[curSlot] * DH + col, avv);
                        cur = l2; curSlot = sbg + r; avv = v;
                    }
                }
                if (cur < SEGCAP) atomicAdd(&ldsAgg[cur][col], avv);
                else atomicAdd(agg + (size_t)sDst[curSlot] * DH + col, avv);
            }
        }
    }

    __syncthreads();

    // flush: interior segments plain store, boundary segments atomicAdd
    const int ns = sNseg;
    const int gmax = (ns < SEGCAP) ? ns : SEGCAP;
    for (int idx = tid; idx < (gmax << 7); idx += 256) {
        const int g = idx >> 7, col = idx & 127;
        const float v = ldsAgg[g][col];
        const int dst = sDst[sSegStart[g]];
        float* p = agg + (size_t)dst * DH + col;
        if (sorted && g > 0 && g < ns - 1) *p = v;
        else atomicAdd(p, v);
    }
}

// ---------------------------------------------------------------------------
// Node MLP via MFMA + residual + LayerNorm.
// ---------------------------------------------------------------------------
__global__ __launch_bounds__(256) void k_node(
    const float* __restrict__ h, const float* __restrict__ agg,
    const ushort_t* __restrict__ W1hf, const float* __restrict__ bh1,
    const ushort_t* __restrict__ W2hf, const float* __restrict__ bh2,
    const float* __restrict__ ln_g, const float* __restrict__ ln_b,
    float* __restrict__ out, int N)
{
    __shared__ __align__(16) ushort_t sIn[64 * 256];
    __shared__ __align__(16) ushort_t sHid[64 * DH];
    const int tid = threadIdx.x;
    const int nblk = blockIdx.x * 64;

    {
        const int row = tid >> 2, q = tid & 3;
        const int gn = nblk + row;
        const float4* ps = (q < 2) ? (const float4*)(h + (size_t)gn * DH + 64 * q)
                                   : (const float4*)(agg + (size_t)gn * DH + 64 * (q - 2));
        uint4* rowp = (uint4*)(sIn + row * 256);
        const int swz = row & 7;
#pragma unroll
        for (int i = 0; i < 8; ++i) {
            uint4 o = make_uint4(0, 0, 0, 0);
            if (gn < N) {
                const float4 g0 = ps[2 * i], g1 = ps[2 * i + 1];
                o.x = pk_bf16(g0.x, g0.y); o.y = pk_bf16(g0.z, g0.w);
                o.z = pk_bf16(g1.x, g1.y); o.w = pk_bf16(g1.z, g1.w);
            }
            rowp[(8 * q + i) ^ swz] = o;
        }
    }
    __syncthreads();

    const int lane = tid & 63, wv = tid >> 6;
    const int lr = lane & 15, lg = lane >> 4;
    const int m0l = wv * 16;

    union FragU { unsigned u[4]; short8 s8; };

    floatx4 acc[8];
#pragma unroll
    for (int ni = 0; ni < 8; ++ni) acc[ni] = (floatx4){0.f, 0.f, 0.f, 0.f};

#pragma unroll
    for (int kc = 0; kc < 8; ++kc) {
        const int b1 = 64 * kc + 8 * lg;
        const int b2 = b1 + 32;
        const int row = m0l + lr;
        const char* rbase = (const char*)(sIn + row * 256);
        const int swz = (row & 7) << 4;
        FragU af;
        const uint2 lo = *(const uint2*)(rbase + ((b1 & ~15) ^ swz) + (b1 & 15));
        const uint2 hi = *(const uint2*)(rbase + ((b2 & ~15) ^ swz) + (b2 & 15));
        af.u[0] = lo.x; af.u[1] = lo.y; af.u[2] = hi.x; af.u[3] = hi.y;
        const ushort_t* wbase = W1hf + ((size_t)(kc * 4 + lg) * 128 + lr) * 8;
        __builtin_amdgcn_s_setprio(1);
#pragma unroll
        for (int ni = 0; ni < 8; ++ni) {
            const short8 bf = *(const short8*)(wbase + ni * 128);
            acc[ni] = __builtin_amdgcn_mfma_f32_16x16x32_bf16(af.s8, bf, acc[ni], 0, 0, 0);
        }
        __builtin_amdgcn_s_setprio(0);
    }

    {
        float bh1v[8];
#pragma unroll
        for (int ni = 0; ni < 8; ++ni) bh1v[ni] = bh1[ni * 16 + lr];
#pragma unroll
        for (int r = 0; r < 4; ++r) {
            const int row = m0l + 4 * lg + r;
            const int swz = row & 7;
            ushort_t* rp = sHid + row * DH;
#pragma unroll
            for (int ni = 0; ni < 8; ++ni) {
                const int col = ni * 16 + lr;
                rp[(((col >> 3) ^ swz) << 3) + (col & 7)] =
                    f2bf1(silu_f(acc[ni][r] + bh1v[ni]));
            }
        }
    }

    floatx4 acc2[8];
#pragma unroll
    for (int ni = 0; ni < 8; ++ni) acc2[ni] = (floatx4){0.f, 0.f, 0.f, 0.f};

#pragma unroll
    for (int kc = 0; kc < 4; ++kc) {
        const int b1 = 64 * kc + 8 * lg;
        const int b2 = b1 + 32;
        const int row = m0l + lr;
        const char* rbase = (const char*)(sHid + row * DH);
        const int swz = (row & 7) << 4;
        FragU af;
        const uint2 lo = *(const uint2*)(rbase + ((b1 & ~15) ^ swz) + (b1 & 15));
        const uint2 hi = *(const uint2*)(rbase + ((b2 & ~15) ^ swz) + (b2 & 15));
        af.u[0] = lo.x; af.u[1] = lo.y; af.u[2] = hi.x; af.u[3] = hi.y;
        const ushort_t* wbase = W2hf + ((size_t)(kc * 4 + lg) * 128 + lr) * 8;
        __builtin_amdgcn_s_setprio(1);
#pragma unroll
        for (int ni = 0; ni < 8; ++ni) {
            const short8 bf = *(const short8*)(wbase + ni * 128);
            acc2[ni] = __builtin_amdgcn_mfma_f32_16x16x32_bf16(af.s8, bf, acc2[ni], 0, 0, 0);
        }
        __builtin_amdgcn_s_setprio(0);
    }

    float gv[8], bv[8], b2v[8];
#pragma unroll
    for (int ni = 0; ni < 8; ++ni) {
        const int col = ni * 16 + lr;
        gv[ni] = ln_g[col]; bv[ni] = ln_b[col]; b2v[ni] = bh2[col];
    }
#pragma unroll
    for (int r = 0; r < 4; ++r) {
        const int row = m0l + 4 * lg + r;
        const int gn = nblk + row;
        const int swz = row & 7;
        float z[8];
        float s1 = 0.f, s2 = 0.f;
#pragma unroll
        for (int ni = 0; ni < 8; ++ni) {
            const int col = ni * 16 + lr;
            const float hv = bf2f(sIn[row * 256 + (((col >> 3) ^ swz) << 3) + (col & 7)]);
            z[ni] = acc2[ni][r] + b2v[ni] + hv;
            s1 += z[ni]; s2 += z[ni] * z[ni];
        }
#pragma unroll
        for (int m = 1; m < 16; m <<= 1) {
            s1 += __shfl_xor(s1, m, 64);
            s2 += __shfl_xor(s2, m, 64);
        }
        const float mean = s1 * (1.f / 128.f);
        const float var = s2 * (1.f / 128.f) - mean * mean;
        const float rstd = rsqrtf(var + 1e-5f);
        if (gn < N) {
#pragma unroll
            for (int ni = 0; ni < 8; ++ni) {
                const int col = ni * 16 + lr;
                out[(size_t)gn * DH + col] = (z[ni] - mean) * rstd * gv[ni] + bv[ni];
            }
        }
    }
}

extern "C" void kernel_launch(void* const* d_in, const int* in_sizes, int n_in,
                              void* d_out, int out_size, void* d_ws, size_t ws_size,
                              hipStream_t stream)
{
    (void)n_in; (void)out_size;
    const float* h   = (const float*)d_in[0];
    const float* x   = (const float*)d_in[1];
    const int*   ei  = (const int*)d_in[2];
    const float* ew  = (const float*)d_in[3];
    const float* Wm1 = (const float*)d_in[4];
    const float* bm1 = (const float*)d_in[5];
    const float* Wm2 = (const float*)d_in[6];
    const float* bm2 = (const float*)d_in[7];
    const float* Wh1 = (const float*)d_in[8];
    const float* bh1 = (const float*)d_in[9];
    const float* Wh2 = (const float*)d_in[10];
    const float* bh2 = (const float*)d_in[11];
    const float* lng = (const float*)d_in[12];
    const float* lnb = (const float*)d_in[13];
    float* out = (float*)d_out;

    const int N = in_sizes[0] / DH;
    const int E = in_sizes[3];

    // ws: agg | counts | cursor | Abf | Bbf | W2f | Tbf | W1mf | W1hf | W2hf | epk
    float*    agg  = (float*)d_ws;
    int*   counts  = (int*)(agg + (size_t)N * DH);
    int*   cursor  = counts + N;
    ushort_t* Abf  = (ushort_t*)((((uintptr_t)(cursor + N)) + 15) & ~(uintptr_t)15);
    ushort_t* Bbf  = Abf + (size_t)N * DH;
    ushort_t* W2f  = Bbf + (size_t)N * DH;
    ushort_t* Tbf  = W2f + 16384;
    ushort_t* W1mf = Tbf + (size_t)NTAB * DH;
    ushort_t* W1hf = W1mf + 32768;
    ushort_t* W2hf = W1hf + 32768;
    uint4* epk     = (uint4*)((((uintptr_t)(W2hf + 16384)) + 15) & ~(uintptr_t)15);

    const size_t need = ((char*)(epk + E)) - ((char*)d_ws);
    const int use_sort = (ws_size >= need) ? 1 : 0;
    const int pack = use_sort && (N <= 65535);

    const int nb_hist = use_sort ? (E + 255) / 256 : 0;
    const int nb_prep = 257 + 8 + 16 + 16 + 8;
    const int nb_scat = nb_hist;
    const int nb_pre  = (N + 63) / 64;

    // one memset covers agg and (contiguous) counts
    hipMemsetAsync(agg, 0, (size_t)N * DH * sizeof(float) + (use_sort ? (size_t)N * 4 : 0), stream);
    k_hist_prep<<<nb_hist + nb_prep, 256, 0, stream>>>(ei, counts, E, Wm1, Wm2, Wh1, Wh2,
                                                       Tbf, W2f, W1mf, W1hf, W2hf, nb_hist);
    if (use_sort)
        k_scan<<<1, 1024, 0, stream>>>(counts, cursor, N);
    k_scatter_pre<<<nb_scat + nb_pre, 256, 0, stream>>>(ei, ew, x, cursor, epk, E, pack,
                                                        h, bm1, W1mf, Abf, Bbf, N, nb_scat);
    k_edge<<<(E + EB - 1) / EB, 256, 0, stream>>>(x, ei, ew, epk,
                                                  W2f, bm2, Abf, Bbf, Tbf, agg,
                                                  use_sort, pack, N, E);
    k_node<<<(N + 63) / 64, 256, 0, stream>>>(h, agg, W1hf, bh1, W2hf, bh2, lng, lnb, out, N);
}

// Round 15
// 384.959 us; speedup vs baseline: 1.1129x; 1.0487x over previous
//
#include <hip/hip_runtime.h>
#include <hip/hip_bf16.h>
#include <math.h>

#define DH 128
#define NRBF 16
#define EB 256     // edges per gemm block (4 waves x 64 edges, 4 subtiles of 16)
#define NTAB 1025
#define SEGCAP 32  // max LDS-resident dst segments per block

typedef unsigned short ushort_t;
typedef __attribute__((ext_vector_type(8))) short short8;
typedef __attribute__((ext_vector_type(4))) float floatx4;

__device__ __forceinline__ float silu_f(float v) {
    return v / (1.f + __expf(-v));
}
__device__ __forceinline__ unsigned pk_bf16(float lo, float hi) {
    __hip_bfloat162 h = __float22bfloat162_rn(make_float2(lo, hi));
    union { __hip_bfloat162 h2; unsigned u; } cv;
    cv.h2 = h;
    return cv.u;
}
__device__ __forceinline__ ushort_t f2bf1(float f) {
    unsigned u = __float_as_uint(f);
    u += 0x7FFFu + ((u >> 16) & 1u);
    return (ushort_t)(u >> 16);
}
__device__ __forceinline__ float bflo(unsigned u) { return __uint_as_float(u << 16); }
__device__ __forceinline__ float bfhi(unsigned u) { return __uint_as_float(u & 0xffff0000u); }
__device__ __forceinline__ float bf2f(ushort_t u) { return __uint_as_float(((unsigned)u) << 16); }

__device__ __forceinline__ int detect64(const int* __restrict__ ei) {
    int z = 0;
#pragma unroll
    for (int i = 0; i < 8; ++i) z |= ei[2 * i + 1];
    return (z == 0) ? 1 : 0;
}
__device__ __forceinline__ int load_dst(const int* ei, int is64, int e, int E) {
    return is64 ? ei[2 * E + 2 * e] : ei[E + e];
}
__device__ __forceinline__ int load_src(const int* ei, int is64, int e, int E) {
    return is64 ? ei[2 * e] : ei[e];
}

// ---------------------------------------------------------------------------
// Merged prep: histogram | Tbf rows (4/block) | W2f | W1mf | W1hf | W2hf
// ---------------------------------------------------------------------------
__global__ __launch_bounds__(256) void k_hist_prep(
    const int* __restrict__ ei, int* __restrict__ counts, int E,
    const float* __restrict__ Wm1, const float* __restrict__ Wm2,
    const float* __restrict__ Wh1, const float* __restrict__ Wh2,
    ushort_t* __restrict__ Tbf, ushort_t* __restrict__ W2f,
    ushort_t* __restrict__ W1mf, ushort_t* __restrict__ W1hf,
    ushort_t* __restrict__ W2hf, int nb_hist)
{
    const int b = blockIdx.x, tid = threadIdx.x;
    if (b < nb_hist) {
        const int e = b * 256 + tid;
        if (e < E) {
            const int is64 = detect64(ei);
            atomicAdd(&counts[load_dst(ei, is64, e, E)], 1);
        }
        return;
    }
    int b2 = b - nb_hist;
    if (b2 < 257) {
        const int i = b2 * 4 + (tid >> 6);
        if (i < NTAB) {
            const float WIDTH = 0.09428090415820634f;
            const float GAMMA = 56.25f;
            const float DELTA = 1.4142135623730951f / 1024.0f;
            const float r = (float)i * DELTA;
            const int c0 = (tid & 63) * 2;
            float a0 = 0.f, a1 = 0.f;
#pragma unroll
            for (int q = 0; q < NRBF; ++q) {
                const float dr = r - (float)q * WIDTH;
                const float w = __expf(-GAMMA * dr * dr);
                a0 = fmaf(w, Wm1[(256 + q) * DH + c0], a0);
                a1 = fmaf(w, Wm1[(256 + q) * DH + c0 + 1], a1);
            }
            *(unsigned*)(Tbf + (size_t)i * DH + c0) = pk_bf16(a0, a1);
        }
        return;
    }
    b2 -= 257;
    if (b2 < 8) {
        const int u = b2 * 256 + tid;
        const int col = u & 127, kclg = u >> 7;
        const int lg = kclg & 3, kc = kclg >> 2;
        unsigned o[4];
#pragma unroll
        for (int j = 0; j < 2; ++j) {
            o[j]     = pk_bf16(Wm2[(kc * 32 + 4 * lg + 2 * j) * DH + col],
                               Wm2[(kc * 32 + 4 * lg + 2 * j + 1) * DH + col]);
            o[2 + j] = pk_bf16(Wm2[(kc * 32 + 16 + 4 * lg + 2 * j) * DH + col],
                               Wm2[(kc * 32 + 16 + 4 * lg + 2 * j + 1) * DH + col]);
        }
        *(uint4*)(W2f + 8 * u) = make_uint4(o[0], o[1], o[2], o[3]);
        return;
    }
    b2 -= 8;
    if (b2 < 16) {
        const int u = b2 * 256 + tid;
        const int c = u & 255, kclg = u >> 8;
        const int lg = kclg & 3, kc = kclg >> 2;
        const int base = (c < 128) ? 0 : 128;
        const int cc = c & 127;
        unsigned o[4];
#pragma unroll
        for (int j = 0; j < 2; ++j) {
            o[j]     = pk_bf16(Wm1[(base + kc * 32 + 4 * lg + 2 * j) * DH + cc],
                               Wm1[(base + kc * 32 + 4 * lg + 2 * j + 1) * DH + cc]);
            o[2 + j] = pk_bf16(Wm1[(base + kc * 32 + 16 + 4 * lg + 2 * j) * DH + cc],
                               Wm1[(base + kc * 32 + 16 + 4 * lg + 2 * j + 1) * DH + cc]);
        }
        *(uint4*)(W1mf + 8 * u) = make_uint4(o[0], o[1], o[2], o[3]);
        return;
    }
    b2 -= 16;
    if (b2 < 16) {
        const int u = b2 * 256 + tid;
        const int col = u & 127, kclg = u >> 7;
        const int lg = kclg & 3, kc = kclg >> 2;
        unsigned o[4];
#pragma unroll
        for (int j = 0; j < 2; ++j) {
            o[j]     = pk_bf16(Wh1[(kc * 32 + 4 * lg + 2 * j) * DH + col],
                               Wh1[(kc * 32 + 4 * lg + 2 * j + 1) * DH + col]);
            o[2 + j] = pk_bf16(Wh1[(kc * 32 + 16 + 4 * lg + 2 * j) * DH + col],
                               Wh1[(kc * 32 + 16 + 4 * lg + 2 * j + 1) * DH + col]);
        }
        *(uint4*)(W1hf + 8 * u) = make_uint4(o[0], o[1], o[2], o[3]);
        return;
    }
    b2 -= 16;
    {
        const int u = b2 * 256 + tid;
        const int col = u & 127, kclg = u >> 7;
        const int lg = kclg & 3, kc = kclg >> 2;
        unsigned o[4];
#pragma unroll
        for (int j = 0; j < 2; ++j) {
            o[j]     = pk_bf16(Wh2[(kc * 32 + 4 * lg + 2 * j) * DH + col],
                               Wh2[(kc * 32 + 4 * lg + 2 * j + 1) * DH + col]);
            o[2 + j] = pk_bf16(Wh2[(kc * 32 + 16 + 4 * lg + 2 * j) * DH + col],
                               Wh2[(kc * 32 + 16 + 4 * lg + 2 * j + 1) * DH + col]);
        }
        *(uint4*)(W2hf + 8 * u) = make_uint4(o[0], o[1], o[2], o[3]);
    }
}

// ---------------------------------------------------------------------------
// Exclusive prefix sum of counts -> cursor.
// ---------------------------------------------------------------------------
__global__ __launch_bounds__(1024) void k_scan(const int* __restrict__ counts,
                                               int* __restrict__ cursor, int N) {
    __shared__ int wsum[16];
    __shared__ int sCarry;
    const int tid = threadIdx.x, lane = tid & 63, wid = tid >> 6;
    if (tid == 0) sCarry = 0;
    __syncthreads();
    for (int c0 = 0; c0 < N; c0 += 4096) {
        const int idx = c0 + tid * 4;
        int4 v = make_int4(0, 0, 0, 0);
        if (idx < N) v = *(const int4*)(counts + idx);
        const int t01 = v.x + v.y;
        const int t012 = t01 + v.z;
        const int tot = t012 + v.w;
        int incl = tot;
#pragma unroll
        for (int d = 1; d < 64; d <<= 1) {
            int t = __shfl_up(incl, d, 64);
            if (lane >= d) incl += t;
        }
        if (lane == 63) wsum[wid] = incl;
        __syncthreads();
        if (wid == 0) {
            int s = (lane < 16) ? wsum[lane] : 0;
#pragma unroll
            for (int d = 1; d < 16; d <<= 1) {
                int t = __shfl_up(s, d, 64);
                if (lane >= d) s += t;
            }
            if (lane < 16) wsum[lane] = s;
        }
        __syncthreads();
        const int ex = sCarry + (wid > 0 ? wsum[wid - 1] : 0) + incl - tot;
        if (idx + 3 < N) {
            *(int4*)(cursor + idx) = make_int4(ex, ex + v.x, ex + t01, ex + t012);
        } else if (idx < N) {
            cursor[idx] = ex;
            if (idx + 1 < N) cursor[idx + 1] = ex + v.x;
            if (idx + 2 < N) cursor[idx + 2] = ex + t01;
        }
        __syncthreads();
        if (tid == 0) sCarry += wsum[15];
        __syncthreads();
    }
}

// ---------------------------------------------------------------------------
// Merged: scatter packed 16B payloads | MFMA precompute A/B -> bf16
// ---------------------------------------------------------------------------
__global__ __launch_bounds__(256) void k_scatter_pre(
    const int* __restrict__ ei, const float* __restrict__ ew, const float* __restrict__ x,
    int* __restrict__ cursor, uint4* __restrict__ epk,
    int E, int pack,
    const float* __restrict__ h, const float* __restrict__ bm1,
    const ushort_t* __restrict__ W1mf,
    ushort_t* __restrict__ Abf, ushort_t* __restrict__ Bbf, int N, int nb_scat)
{
    const int tid = threadIdx.x;

    if ((int)blockIdx.x < nb_scat) {
        const int e = blockIdx.x * 256 + tid;
        if (e < E) {
            const int is64 = detect64(ei);
            const int s = load_src(ei, is64, e, E);
            const int d = load_dst(ei, is64, e, E);
            const int pos = atomicAdd(&cursor[d], 1);
            unsigned x0 = (unsigned)s;
            if (pack) {
                const float2 xs = *(const float2*)(x + 2 * s);
                const float2 xd = *(const float2*)(x + 2 * d);
                const float dxv = xs.x - xd.x, dyv = xs.y - xd.y;
                const float r = sqrtf(dxv * dxv + dyv * dyv + 1e-8f);
                int ti = (int)(r * 724.0773439350246f + 0.5f);
                ti = min(ti, NTAB - 1);
                x0 |= ((unsigned)ti << 16);
            }
            epk[pos] = make_uint4(x0, __float_as_uint(ew[e]), (unsigned)d, 0u);
        }
        return;
    }

    __shared__ __align__(16) ushort_t sIn[64 * DH];
    const int nblk = ((int)blockIdx.x - nb_scat) * 64;

    {
        const int row = tid >> 2, q = tid & 3;
        const int gn = nblk + row;
        const float4* ps = (const float4*)(h + (size_t)gn * DH + 32 * q);
        uint4* rowp = (uint4*)(sIn + row * DH);
        const int swz = row & 7;
#pragma unroll
        for (int i = 0; i < 4; ++i) {
            uint4 o = make_uint4(0, 0, 0, 0);
            if (gn < N) {
                const float4 g0 = ps[2 * i], g1 = ps[2 * i + 1];
                o.x = pk_bf16(g0.x, g0.y); o.y = pk_bf16(g0.z, g0.w);
                o.z = pk_bf16(g1.x, g1.y); o.w = pk_bf16(g1.z, g1.w);
            }
            rowp[(4 * q + i) ^ swz] = o;
        }
    }
    __syncthreads();

    const int lane = tid & 63, wv = tid >> 6;
    const int lr = lane & 15, lg = lane >> 4;
    const int m0l = wv * 16;

    union FragU { unsigned u[4]; short8 s8; };
    floatx4 acc[16];
#pragma unroll
    for (int ni = 0; ni < 16; ++ni) acc[ni] = (floatx4){0.f, 0.f, 0.f, 0.f};

#pragma unroll
    for (int kc = 0; kc < 4; ++kc) {
        const int b1 = 64 * kc + 8 * lg;
        const int b2 = b1 + 32;
        const int row = m0l + lr;
        const char* rbase = (const char*)(sIn + row * DH);
        const int swz = (row & 7) << 4;
        FragU af;
        const uint2 lo = *(const uint2*)(rbase + ((b1 & ~15) ^ swz) + (b1 & 15));
        const uint2 hi = *(const uint2*)(rbase + ((b2 & ~15) ^ swz) + (b2 & 15));
        af.u[0] = lo.x; af.u[1] = lo.y; af.u[2] = hi.x; af.u[3] = hi.y;
        const ushort_t* wbase = W1mf + ((size_t)(kc * 4 + lg) * 256 + lr) * 8;
        __builtin_amdgcn_s_setprio(1);
#pragma unroll
        for (int ni = 0; ni < 16; ++ni) {
            const short8 bf = *(const short8*)(wbase + ni * 128);
            acc[ni] = __builtin_amdgcn_mfma_f32_16x16x32_bf16(af.s8, bf, acc[ni], 0, 0, 0);
        }
        __builtin_amdgcn_s_setprio(0);
    }

    float bm1v[8];
#pragma unroll
    for (int ni = 0; ni < 8; ++ni) bm1v[ni] = bm1[ni * 16 + lr];
#pragma unroll
    for (int r = 0; r < 4; ++r) {
        const int gn = nblk + m0l + 4 * lg + r;
        if (gn < N) {
#pragma unroll
            for (int ni = 0; ni < 8; ++ni)
                Abf[(size_t)gn * DH + ni * 16 + lr] = f2bf1(acc[ni][r] + bm1v[ni]);
#pragma unroll
            for (int ni = 8; ni < 16; ++ni)
                Bbf[(size_t)gn * DH + (ni - 8) * 16 + lr] = f2bf1(acc[ni][r]);
        }
    }
}

// ---------------------------------------------------------------------------
// k_build: 4 threads/edge gather+build hidden, streaming bf16 write to Hbf.
// No LDS, no MFMA -> high occupancy, all gathers in flight.
// Hbf row = sorted slot; 16B chunks stored at position (chunk ^ (slot&7)).
// ---------------------------------------------------------------------------
__global__ __launch_bounds__(256) void k_build(
    const float* __restrict__ x, const uint4* __restrict__ epk,
    const ushort_t* __restrict__ Abf, const ushort_t* __restrict__ Bbf,
    const ushort_t* __restrict__ Tbf, ushort_t* __restrict__ Hbf,
    int pack, int E)
{
    const int gid = blockIdx.x * 256 + threadIdx.x;
    const int e = gid >> 2, q = gid & 3;
    if (e >= E) return;

    const uint4 v = epk[e];
    const int d = (int)v.z;
    int s, ti;
    if (pack) { s = (int)(v.x & 0xFFFFu); ti = (int)(v.x >> 16); }
    else {
        s = (int)v.x;
        const float2 xs = *(const float2*)(x + 2 * s);
        const float2 xd = *(const float2*)(x + 2 * d);
        const float dxv = xs.x - xd.x, dyv = xs.y - xd.y;
        const float r = sqrtf(dxv * dxv + dyv * dyv + 1e-8f);
        ti = min((int)(r * 724.0773439350246f + 0.5f), NTAB - 1);
    }

    const uint4* pA = (const uint4*)(Abf + (size_t)s * DH + 32 * q);
    const uint4* pB = (const uint4*)(Bbf + (size_t)d * DH + 32 * q);
    const uint4* pT = (const uint4*)(Tbf + (size_t)ti * DH + 32 * q);
    uint4 av[4], bv[4], tv[4];
#pragma unroll
    for (int i = 0; i < 4; ++i) { av[i] = pA[i]; bv[i] = pB[i]; tv[i] = pT[i]; }

    uint4* rowp = (uint4*)(Hbf + (size_t)e * DH);
    const int swz = e & 7;
#pragma unroll
    for (int i = 0; i < 4; ++i) {
        const uint4 a = av[i]; const uint4 b = bv[i]; const uint4 t = tv[i];
        const float v0 = bflo(a.x) + bflo(b.x) + bflo(t.x);
        const float v1 = bfhi(a.x) + bfhi(b.x) + bfhi(t.x);
        const float v2 = bflo(a.y) + bflo(b.y) + bflo(t.y);
        const float v3 = bfhi(a.y) + bfhi(b.y) + bfhi(t.y);
        const float v4 = bflo(a.z) + bflo(b.z) + bflo(t.z);
        const float v5 = bfhi(a.z) + bfhi(b.z) + bfhi(t.z);
        const float v6 = bflo(a.w) + bflo(b.w) + bflo(t.w);
        const float v7 = bfhi(a.w) + bfhi(b.w) + bfhi(t.w);
        uint4 pk;
        pk.x = pk_bf16(silu_f(v0), silu_f(v1));
        pk.y = pk_bf16(silu_f(v2), silu_f(v3));
        pk.z = pk_bf16(silu_f(v4), silu_f(v5));
        pk.w = pk_bf16(silu_f(v6), silu_f(v7));
        rowp[(4 * q + i) ^ swz] = pk;
    }
}

// ---------------------------------------------------------------------------
// k_gemm: reads pre-built (pre-swizzled) hidden rows from Hbf -> LDS (identity
// copy, coalesced), MFMA vs W2f (global, L2-hot), lid-scan + LDS segment agg.
// Light registers -> 4 blocks/CU.
// ---------------------------------------------------------------------------
__global__ __launch_bounds__(256, 4) void k_gemm(
    const uint4* __restrict__ epk, const ushort_t* __restrict__ Hbf,
    const ushort_t* __restrict__ W2f, const float* __restrict__ bm2,
    float* __restrict__ agg, int N, int E)
{
    __shared__ __align__(16) ushort_t sHid[4][16 * DH];   // 16 KB per-wave slices
    __shared__ __align__(16) float ldsAgg[SEGCAP][DH];    // 16 KB
    __shared__ int   sDst[EB];
    __shared__ int   sLid[EB];
    __shared__ float sEw[EB];
    __shared__ int   sSegStart[SEGCAP];
    __shared__ int   sNseg;
    __shared__ int   sWtot[4];

    const int tid  = threadIdx.x;
    const int lane = tid & 63;
    const int wv   = tid >> 6;
    const int lr   = lane & 15;
    const int lg   = lane >> 4;
    const int e4   = lane >> 2;    // edge within 16-edge subtile
    const int q    = lane & 3;     // col quarter
    const int wbase = wv * 64;

    // XCD-chunked bijective swizzle
    const int nwg = gridDim.x;
    const int xcd = blockIdx.x & 7;
    const int cidx = blockIdx.x >> 3;
    const int qch = nwg >> 3, rch = nwg & 7;
    const int bid = (xcd < rch) ? (xcd * (qch + 1) + cidx)
                                : (rch * (qch + 1) + (xcd - rch) * qch + cidx);
    const int e0 = bid * EB;

    // zero ldsAgg
    {
        const float4 z = make_float4(0.f, 0.f, 0.f, 0.f);
        float4* za = (float4*)&ldsAgg[0][0];
#pragma unroll
        for (int i = 0; i < 4; ++i) za[tid + 256 * i] = z;
    }

    // staging (dst/ew only)
    {
        const int slot = e0 + tid;
        int d;
        float w = 0.f;
        if (slot < E) {
            const uint4 v = epk[slot];
            w = __uint_as_float(v.y);
            d = (int)v.z;
        } else {
            d = (int)epk[E - 1].z;
        }
        sDst[tid] = d; sEw[tid] = w;
    }
    __syncthreads();

    // lid segment scan over 256 slots
    {
        const int bflag = (tid > 0) && (sDst[tid] != sDst[tid - 1]);
        int incl = bflag;
#pragma unroll
        for (int dd = 1; dd < 64; dd <<= 1) {
            int t = __shfl_up(incl, dd, 64);
            if (lane >= dd) incl += t;
        }
        if (lane == 63) sWtot[wv] = incl;
        __syncthreads();
        int off = 0;
#pragma unroll
        for (int wq = 0; wq < 3; ++wq)
            if (wq < wv) off += sWtot[wq];
        incl += off;
        sLid[tid] = incl;
        if ((bflag || tid == 0) && incl < SEGCAP) sSegStart[incl] = tid;
        if (tid == EB - 1) sNseg = incl + 1;
    }
    __syncthreads();

    float bc8[8];
#pragma unroll
    for (int ni = 0; ni < 8; ++ni) bc8[ni] = bm2[ni * 16 + lr];

    union FragU { unsigned u[4]; short8 s8; };
    ushort_t* slice = &sHid[wv][0];
    floatx4 acc[8];

#pragma unroll
    for (int st = 0; st < 4; ++st) {
        const int sb = wbase + st * 16;
        const int le = sb + e4;

        // identity copy Hbf row -> LDS slice (pre-swizzled; chunk perm for banks)
        {
            const uint4* gsrc = (const uint4*)(Hbf + (size_t)(e0 + le) * DH);
            uint4* rowp = (uint4*)(slice + e4 * DH);
            const int swz = e4 & 7;
#pragma unroll
            for (int i = 0; i < 4; ++i) {
                const int c = (4 * q + i) ^ swz;
                rowp[c] = gsrc[c];
            }
        }
        // no barrier: wave reads only rows it wrote

        // MFMA: A from LDS, B from global W2f (L2-hot)
#pragma unroll
        for (int ni = 0; ni < 8; ++ni) acc[ni] = (floatx4){0.f, 0.f, 0.f, 0.f};
#pragma unroll
        for (int kc = 0; kc < 4; ++kc) {
            const int bo1 = 64 * kc + 8 * lg;
            const int bo2 = bo1 + 32;
            const char* rbase = (const char*)(slice + lr * DH);
            const int swzf = (lr & 7) << 4;
            FragU af;
            const uint2 lo = *(const uint2*)(rbase + ((bo1 & ~15) ^ swzf) + (bo1 & 15));
            const uint2 hi = *(const uint2*)(rbase + ((bo2 & ~15) ^ swzf) + (bo2 & 15));
            af.u[0] = lo.x; af.u[1] = lo.y; af.u[2] = hi.x; af.u[3] = hi.y;
            const ushort_t* wb2 = W2f + ((size_t)(kc * 4 + lg) * 128 + lr) * 8;
            __builtin_amdgcn_s_setprio(1);
#pragma unroll
            for (int ni = 0; ni < 8; ++ni) {
                const short8 bf = *(const short8*)(wb2 + ni * 128);
                acc[ni] = __builtin_amdgcn_mfma_f32_16x16x32_bf16(af.s8, bf, acc[ni], 0, 0, 0);
            }
            __builtin_amdgcn_s_setprio(0);
        }

        // run-merge by lid -> LDS segment accumulation
        {
            const int sbg = sb + 4 * lg;
            int lid4[4]; float ew4[4];
#pragma unroll
            for (int r = 0; r < 4; ++r) { lid4[r] = sLid[sbg + r]; ew4[r] = sEw[sbg + r]; }
#pragma unroll
            for (int ni = 0; ni < 8; ++ni) {
                const int col = ni * 16 + lr;
                const float bc = bc8[ni];
                int cur = lid4[0], curSlot = sbg;
                float avv = (acc[ni][0] + bc) * ew4[0];
#pragma unroll
                for (int r = 1; r < 4; ++r) {
                    const int l2 = lid4[r];
                    const float v = (acc[ni][r] + bc) * ew4[r];
                    if (l2 == cur) avv += v;
                    else {
                        if (cur < SEGCAP) atomicAdd(&ldsAgg[cur][col], avv);
                        else atomicAdd(agg + (size_t)sDst[curSlot] * DH + col, avv);
                        cur = l2; curSlot = sbg + r; avv = v;
                    }
                }
                if (cur < SEGCAP) atomicAdd(&ldsAgg[cur][col], avv);
                else atomicAdd(agg + (size_t)sDst[curSlot] * DH + col, avv);
            }
        }
    }

    __syncthreads();

    // flush: interior segments plain store, boundary segments atomicAdd
    const int ns = sNseg;
    const int gmax = (ns < SEGCAP) ? ns : SEGCAP;
    for (int idx = tid; idx < (gmax << 7); idx += 256) {
        const int g = idx >> 7, col = idx & 127;
        const float v = ldsAgg[g][col];
        const int dst = sDst[sSegStart[g]];
        float* p = agg + (size_t)dst * DH + col;
        if (g > 0 && g < ns - 1) *p = v;
        else atomicAdd(p, v);
    }
}

// ---------------------------------------------------------------------------
// Fallback monolithic edge kernel (R12 structure) for when ws can't fit Hbf.
// ---------------------------------------------------------------------------
__global__ __launch_bounds__(256, 2) void k_edge_mono(
    const float* __restrict__ x, const int* __restrict__ ei, const float* __restrict__ ew,
    const uint4* __restrict__ epk,
    const ushort_t* __restrict__ W2f, const float* __restrict__ bm2,
    const ushort_t* __restrict__ Abf, const ushort_t* __restrict__ Bbf,
    const ushort_t* __restrict__ Tbf, float* __restrict__ agg,
    int sorted, int pack, int N, int E)
{
    __shared__ __align__(16) ushort_t sHid[4][16 * DH];
    __shared__ __align__(16) float ldsAgg[SEGCAP][DH];
    __shared__ int   sSrc[EB];
    __shared__ int   sDst[EB];
    __shared__ int   sLid[EB];
    __shared__ int   sTi[EB];
    __shared__ float sEw[EB];
    __shared__ int   sSegStart[SEGCAP];
    __shared__ int   sNseg;
    __shared__ int   sWtot[4];

    const int tid  = threadIdx.x;
    const int lane = tid & 63;
    const int wv   = tid >> 6;
    const int lr   = lane & 15;
    const int lg   = lane >> 4;
    const int e4   = lane >> 2;
    const int q    = lane & 3;
    const int wbase = wv * 64;

    const int nwg = gridDim.x;
    const int xcd = blockIdx.x & 7;
    const int cidx = blockIdx.x >> 3;
    const int qch = nwg >> 3, rch = nwg & 7;
    const int bid = (xcd < rch) ? (xcd * (qch + 1) + cidx)
                                : (rch * (qch + 1) + (xcd - rch) * qch + cidx);
    const int e0 = bid * EB;

    {
        const float4 z = make_float4(0.f, 0.f, 0.f, 0.f);
        float4* za = (float4*)&ldsAgg[0][0];
#pragma unroll
        for (int i = 0; i < 4; ++i) za[tid + 256 * i] = z;
    }

    {
        const int slot = e0 + tid;
        int s = 0, d = 0, ti = 0;
        float w = 0.f;
        if (slot < E) {
            if (sorted) {
                const uint4 v = epk[slot];
                w = __uint_as_float(v.y);
                d = (int)v.z;
                if (pack) { s = (int)(v.x & 0xFFFFu); ti = (int)(v.x >> 16); }
                else {
                    s = (int)v.x;
                    const float2 xs = *(const float2*)(x + 2 * s);
                    const float2 xd = *(const float2*)(x + 2 * d);
                    const float dxv = xs.x - xd.x, dyv = xs.y - xd.y;
                    const float r = sqrtf(dxv * dxv + dyv * dyv + 1e-8f);
                    ti = min((int)(r * 724.0773439350246f + 0.5f), NTAB - 1);
                }
            } else {
                const int is64 = detect64(ei);
                s = load_src(ei, is64, slot, E);
                d = load_dst(ei, is64, slot, E);
                w = ew[slot];
                const float2 xs = *(const float2*)(x + 2 * s);
                const float2 xd = *(const float2*)(x + 2 * d);
                const float dxv = xs.x - xd.x, dyv = xs.y - xd.y;
                const float r = sqrtf(dxv * dxv + dyv * dyv + 1e-8f);
                ti = min((int)(r * 724.0773439350246f + 0.5f), NTAB - 1);
            }
        } else {
            d = sorted ? (int)epk[E - 1].z : load_dst(ei, detect64(ei), E - 1, E);
        }
        sSrc[tid] = s; sDst[tid] = d; sEw[tid] = w; sTi[tid] = ti;
    }
    __syncthreads();

    {
        const int bflag = (tid > 0) && (sDst[tid] != sDst[tid - 1]);
        int incl = bflag;
#pragma unroll
        for (int dd = 1; dd < 64; dd <<= 1) {
            int t = __shfl_up(incl, dd, 64);
            if (lane >= dd) incl += t;
        }
        if (lane == 63) sWtot[wv] = incl;
        __syncthreads();
        int off = 0;
#pragma unroll
        for (int wq = 0; wq < 3; ++wq)
            if (wq < wv) off += sWtot[wq];
        incl += off;
        sLid[tid] = incl;
        if ((bflag || tid == 0) && incl < SEGCAP) sSegStart[incl] = tid;
        if (tid == EB - 1) sNseg = incl + 1;
    }
    __syncthreads();

    float bc8[8];
#pragma unroll
    for (int ni = 0; ni < 8; ++ni) bc8[ni] = bm2[ni * 16 + lr];

    union FragU { unsigned u[4]; short8 s8; };
    ushort_t* slice = &sHid[wv][0];
    floatx4 acc[8];

#pragma unroll
    for (int st = 0; st < 4; ++st) {
        const int sb = wbase + st * 16;
        const int le = sb + e4;
        const int s  = sSrc[le];
        const int d  = sDst[le];
        const int ti = sTi[le];
        const uint4* pA = (const uint4*)(Abf + (size_t)s * DH + 32 * q);
        const uint4* pB = (const uint4*)(Bbf + (size_t)d * DH + 32 * q);
        const uint4* pT = (const uint4*)(Tbf + (size_t)ti * DH + 32 * q);
        uint4 av[4], bv[4], tv[4];
#pragma unroll
        for (int i = 0; i < 4; ++i) { av[i] = pA[i]; bv[i] = pB[i]; tv[i] = pT[i]; }

        {
            uint4* rowp = (uint4*)(slice + e4 * DH);
            const int swzw = e4 & 7;
#pragma unroll
            for (int i = 0; i < 4; ++i) {
                const uint4 a = av[i]; const uint4 b = bv[i]; const uint4 t = tv[i];
                const float v0 = bflo(a.x) + bflo(b.x) + bflo(t.x);
                const float v1 = bfhi(a.x) + bfhi(b.x) + bfhi(t.x);
                const float v2 = bflo(a.y) + bflo(b.y) + bflo(t.y);
                const float v3 = bfhi(a.y) + bfhi(b.y) + bfhi(t.y);
                const float v4 = bflo(a.z) + bflo(b.z) + bflo(t.z);
                const float v5 = bfhi(a.z) + bfhi(b.z) + bfhi(t.z);
                const float v6 = bflo(a.w) + bflo(b.w) + bflo(t.w);
                const float v7 = bfhi(a.w) + bfhi(b.w) + bfhi(t.w);
                uint4 pk;
                pk.x = pk_bf16(silu_f(v0), silu_f(v1));
                pk.y = pk_bf16(silu_f(v2), silu_f(v3));
                pk.z = pk_bf16(silu_f(v4), silu_f(v5));
                pk.w = pk_bf16(silu_f(v6), silu_f(v7));
                rowp[(4 * q + i) ^ swzw] = pk;
            }
        }

#pragma unroll
        for (int ni = 0; ni < 8; ++ni) acc[ni] = (floatx4){0.f, 0.f, 0.f, 0.f};
#pragma unroll
        for (int kc = 0; kc < 4; ++kc) {
            const int bo1 = 64 * kc + 8 * lg;
            const int bo2 = bo1 + 32;
            const char* rbase = (const char*)(slice + lr * DH);
            const int swzf = (lr & 7) << 4;
            FragU af;
            const uint2 lo = *(const uint2*)(rbase + ((bo1 & ~15) ^ swzf) + (bo1 & 15));
            const uint2 hi = *(const uint2*)(rbase + ((bo2 & ~15) ^ swzf) + (bo2 & 15));
            af.u[0] = lo.x; af.u[1] = lo.y; af.u[2] = hi.x; af.u[3] = hi.y;
            const ushort_t* wb2 = W2f + ((size_t)(kc * 4 + lg) * 128 + lr) * 8;
            __builtin_amdgcn_s_setprio(1);
#pragma unroll
            for (int ni = 0; ni < 8; ++ni) {
                const short8 bf = *(const short8*)(wb2 + ni * 128);
                acc[ni] = __builtin_amdgcn_mfma_f32_16x16x32_bf16(af.s8, bf, acc[ni], 0, 0, 0);
            }
            __builtin_amdgcn_s_setprio(0);
        }

        {
            const int sbg = sb + 4 * lg;
            int lid4[4]; float ew4[4];
#pragma unroll
            for (int r = 0; r < 4; ++r) { lid4[r] = sLid[sbg + r]; ew4[r] = sEw[sbg + r]; }
#pragma unroll
            for (int ni = 0; ni < 8; ++ni) {
                const int col = ni * 16 + lr;
                const float bc = bc8[ni];
                int cur = lid4[0], curSlot = sbg;
                float avv = (acc[ni][0] + bc) * ew4[0];
#pragma unroll
                for (int r = 1; r < 4; ++r) {
                    const int l2 = lid4[r];
                    const float v = (acc[ni][r] + bc) * ew4[r];
                    if (l2 == cur) avv += v;
                    else {
                        if (cur < SEGCAP) atomicAdd(&ldsAgg[cur][col], avv);
                        else atomicAdd(agg + (size_t)sDst[curSlot] * DH + col, avv);
                        cur = l2; curSlot = sbg + r; avv = v;
                    }
                }
                if (cur < SEGCAP) atomicAdd(&ldsAgg[cur][col], avv);
                else atomicAdd(agg + (size_t)sDst[curSlot] * DH + col, avv);
            }
        }
    }

    __syncthreads();

    const int ns = sNseg;
    const int gmax = (ns < SEGCAP) ? ns : SEGCAP;
    for (int idx = tid; idx < (gmax << 7); idx += 256) {
        const int g = idx >> 7, col = idx & 127;
        const float v = ldsAgg[g][col];
        const int dst = sDst[sSegStart[g]];
        float* p = agg + (size_t)dst * DH + col;
        if (sorted && g > 0 && g < ns - 1) *p = v;
        else atomicAdd(p, v);
    }
}

// ---------------------------------------------------------------------------
// Node MLP via MFMA + residual + LayerNorm.
// ---------------------------------------------------------------------------
__global__ __launch_bounds__(256) void k_node(
    const float* __restrict__ h, const float* __restrict__ agg,
    const ushort_t* __restrict__ W1hf, const float* __restrict__ bh1,
    const ushort_t* __restrict__ W2hf, const float* __restrict__ bh2,
    const float* __restrict__ ln_g, const float* __restrict__ ln_b,
    float* __restrict__ out, int N)
{
    __shared__ __align__(16) ushort_t sIn[64 * 256];
    __shared__ __align__(16) ushort_t sHid[64 * DH];
    const int tid = threadIdx.x;
    const int nblk = blockIdx.x * 64;

    {
        const int row = tid >> 2, q = tid & 3;
        const int gn = nblk + row;
        const float4* ps = (q < 2) ? (const float4*)(h + (size_t)gn * DH + 64 * q)
                                   : (const float4*)(agg + (size_t)gn * DH + 64 * (q - 2));
        uint4* rowp = (uint4*)(sIn + row * 256);
        const int swz = row & 7;
#pragma unroll
        for (int i = 0; i < 8; ++i) {
            uint4 o = make_uint4(0, 0, 0, 0);
            if (gn < N) {
                const float4 g0 = ps[2 * i], g1 = ps[2 * i + 1];
                o.x = pk_bf16(g0.x, g0.y); o.y = pk_bf16(g0.z, g0.w);
                o.z = pk_bf16(g1.x, g1.y); o.w = pk_bf16(g1.z, g1.w);
            }
            rowp[(8 * q + i) ^ swz] = o;
        }
    }
    __syncthreads();

    const int lane = tid & 63, wv = tid >> 6;
    const int lr = lane & 15, lg = lane >> 4;
    const int m0l = wv * 16;

    union FragU { unsigned u[4]; short8 s8; };

    floatx4 acc[8];
#pragma unroll
    for (int ni = 0; ni < 8; ++ni) acc[ni] = (floatx4){0.f, 0.f, 0.f, 0.f};

#pragma unroll
    for (int kc = 0; kc < 8; ++kc) {
        const int b1 = 64 * kc + 8 * lg;
        const int b2 = b1 + 32;
        const int row = m0l + lr;
        const char* rbase = (const char*)(sIn + row * 256);
        const int swz = (row & 7) << 4;
        FragU af;
        const uint2 lo = *(const uint2*)(rbase + ((b1 & ~15) ^ swz) + (b1 & 15));
        const uint2 hi = *(const uint2*)(rbase + ((b2 & ~15) ^ swz) + (b2 & 15));
        af.u[0] = lo.x; af.u[1] = lo.y; af.u[2] = hi.x; af.u[3] = hi.y;
        const ushort_t* wbase = W1hf + ((size_t)(kc * 4 + lg) * 128 + lr) * 8;
        __builtin_amdgcn_s_setprio(1);
#pragma unroll
        for (int ni = 0; ni < 8; ++ni) {
            const short8 bf = *(const short8*)(wbase + ni * 128);
            acc[ni] = __builtin_amdgcn_mfma_f32_16x16x32_bf16(af.s8, bf, acc[ni], 0, 0, 0);
        }
        __builtin_amdgcn_s_setprio(0);
    }

    {
        float bh1v[8];
#pragma unroll
        for (int ni = 0; ni < 8; ++ni) bh1v[ni] = bh1[ni * 16 + lr];
#pragma unroll
        for (int r = 0; r < 4; ++r) {
            const int row = m0l + 4 * lg + r;
            const int swz = row & 7;
            ushort_t* rp = sHid + row * DH;
#pragma unroll
            for (int ni = 0; ni < 8; ++ni) {
                const int col = ni * 16 + lr;
                rp[(((col >> 3) ^ swz) << 3) + (col & 7)] =
                    f2bf1(silu_f(acc[ni][r] + bh1v[ni]));
            }
        }
    }

    floatx4 acc2[8];
#pragma unroll
    for (int ni = 0; ni < 8; ++ni) acc2[ni] = (floatx4){0.f, 0.f, 0.f, 0.f};

#pragma unroll
    for (int kc = 0; kc < 4; ++kc) {
        const int b1 = 64 * kc + 8 * lg;
        const int b2 = b1 + 32;
        const int row = m0l + lr;
        const char* rbase = (const char*)(sHid + row * DH);
        const int swz = (row & 7) << 4;
        FragU af;
        const uint2 lo = *(const uint2*)(rbase + ((b1 & ~15) ^ swz) + (b1 & 15));
        const uint2 hi = *(const uint2*)(rbase + ((b2 & ~15) ^ swz) + (b2 & 15));
        af.u[0] = lo.x; af.u[1] = lo.y; af.u[2] = hi.x; af.u[3] = hi.y;
        const ushort_t* wbase = W2hf + ((size_t)(kc * 4 + lg) * 128 + lr) * 8;
        __builtin_amdgcn_s_setprio(1);
#pragma unroll
        for (int ni = 0; ni < 8; ++ni) {
            const short8 bf = *(const short8*)(wbase + ni * 128);
            acc2[ni] = __builtin_amdgcn_mfma_f32_16x16x32_bf16(af.s8, bf, acc2[ni], 0, 0, 0);
        }
        __builtin_amdgcn_s_setprio(0);
    }

    float gv[8], bv[8], b2v[8];
#pragma unroll
    for (int ni = 0; ni < 8; ++ni) {
        const int col = ni * 16 + lr;
        gv[ni] = ln_g[col]; bv[ni] = ln_b[col]; b2v[ni] = bh2[col];
    }
#pragma unroll
    for (int r = 0; r < 4; ++r) {
        const int row = m0l + 4 * lg + r;
        const int gn = nblk + row;
        const int swz = row & 7;
        float z[8];
        float s1 = 0.f, s2 = 0.f;
#pragma unroll
        for (int ni = 0; ni < 8; ++ni) {
            const int col = ni * 16 + lr;
            const float hv = bf2f(sIn[row * 256 + (((col >> 3) ^ swz) << 3) + (col & 7)]);
            z[ni] = acc2[ni][r] + b2v[ni] + hv;
            s1 += z[ni]; s2 += z[ni] * z[ni];
        }
#pragma unroll
        for (int m = 1; m < 16; m <<= 1) {
            s1 += __shfl_xor(s1, m, 64);
            s2 += __shfl_xor(s2, m, 64);
        }
        const float mean = s1 * (1.f / 128.f);
        const float var = s2 * (1.f / 128.f) - mean * mean;
        const float rstd = rsqrtf(var + 1e-5f);
        if (gn < N) {
#pragma unroll
            for (int ni = 0; ni < 8; ++ni) {
                const int col = ni * 16 + lr;
                out[(size_t)gn * DH + col] = (z[ni] - mean) * rstd * gv[ni] + bv[ni];
            }
        }
    }
}

extern "C" void kernel_launch(void* const* d_in, const int* in_sizes, int n_in,
                              void* d_out, int out_size, void* d_ws, size_t ws_size,
                              hipStream_t stream)
{
    (void)n_in; (void)out_size;
    const float* h   = (const float*)d_in[0];
    const float* x   = (const float*)d_in[1];
    const int*   ei  = (const int*)d_in[2];
    const float* ew  = (const float*)d_in[3];
    const float* Wm1 = (const float*)d_in[4];
    const float* bm1 = (const float*)d_in[5];
    const float* Wm2 = (const float*)d_in[6];
    const float* bm2 = (const float*)d_in[7];
    const float* Wh1 = (const float*)d_in[8];
    const float* bh1 = (const float*)d_in[9];
    const float* Wh2 = (const float*)d_in[10];
    const float* bh2 = (const float*)d_in[11];
    const float* lng = (const float*)d_in[12];
    const float* lnb = (const float*)d_in[13];
    float* out = (float*)d_out;

    const int N = in_sizes[0] / DH;
    const int E = in_sizes[3];
    const int nbE = (E + EB - 1) / EB;

    // ws: agg | counts | cursor | Abf | Bbf | W2f | Tbf | W1mf | W1hf | W2hf | epk | Hbf
    float*    agg  = (float*)d_ws;
    int*   counts  = (int*)(agg + (size_t)N * DH);
    int*   cursor  = counts + N;
    ushort_t* Abf  = (ushort_t*)((((uintptr_t)(cursor + N)) + 15) & ~(uintptr_t)15);
    ushort_t* Bbf  = Abf + (size_t)N * DH;
    ushort_t* W2f  = Bbf + (size_t)N * DH;
    ushort_t* Tbf  = W2f + 16384;
    ushort_t* W1mf = Tbf + (size_t)NTAB * DH;
    ushort_t* W1hf = W1mf + 32768;
    ushort_t* W2hf = W1hf + 32768;
    uint4* epk     = (uint4*)((((uintptr_t)(W2hf + 16384)) + 15) & ~(uintptr_t)15);
    ushort_t* Hbf  = (ushort_t*)(epk + E);

    const size_t need_sort  = ((char*)(epk + E)) - ((char*)d_ws);
    const size_t need_split = need_sort + (size_t)nbE * EB * DH * sizeof(ushort_t);
    const int use_sort  = (ws_size >= need_sort) ? 1 : 0;
    const int use_split = use_sort && (ws_size >= need_split);
    const int pack = use_sort && (N <= 65535);

    const int nb_hist = use_sort ? (E + 255) / 256 : 0;
    const int nb_prep = 257 + 8 + 16 + 16 + 8;
    const int nb_scat = nb_hist;
    const int nb_pre  = (N + 63) / 64;

    hipMemsetAsync(agg, 0, (size_t)N * DH * sizeof(float) + (use_sort ? (size_t)N * 4 : 0), stream);
    k_hist_prep<<<nb_hist + nb_prep, 256, 0, stream>>>(ei, counts, E, Wm1, Wm2, Wh1, Wh2,
                                                       Tbf, W2f, W1mf, W1hf, W2hf, nb_hist);
    if (use_sort)
        k_scan<<<1, 1024, 0, stream>>>(counts, cursor, N);
    k_scatter_pre<<<nb_scat + nb_pre, 256, 0, stream>>>(ei, ew, x, cursor, epk, E, pack,
                                                        h, bm1, W1mf, Abf, Bbf, N, nb_scat);
    if (use_split) {
        k_build<<<(4 * E + 255) / 256, 256, 0, stream>>>(x, epk, Abf, Bbf, Tbf, Hbf, pack, E);
        k_gemm<<<nbE, 256, 0, stream>>>(epk, Hbf, W2f, bm2, agg, N, E);
    } else {
        k_edge_mono<<<nbE, 256, 0, stream>>>(x, ei, ew, epk, W2f, bm2, Abf, Bbf, Tbf, agg,
                                             use_sort, pack, N, E);
    }
    k_node<<<(N + 63) / 64, 256, 0, stream>>>(h, agg, W1hf, bh1, W2hf, bh2, lng, lnb, out, N);
}